// Round 12
// baseline (520.802 us; speedup 1.0000x reference)
//
#include <hip/hip_runtime.h>
#include <math.h>

#define PI_F 3.14159265358979323846f
#define NPIX 262144   // 512*512

typedef __attribute__((ext_vector_type(8))) short sh8;
typedef __attribute__((ext_vector_type(4))) float fx4;

__device__ __forceinline__ unsigned short f2bf(float v) {
    unsigned u = __float_as_uint(v);
    return (unsigned short)((u + 0x7FFFu + ((u >> 16) & 1)) >> 16);
}
__device__ __forceinline__ float bf2f(unsigned short h) {
    return __uint_as_float((unsigned)h << 16);
}

// ---------------------------------------------------------------- dark channel
__global__ __launch_bounds__(256) void k_minc(const float* __restrict__ x, float* __restrict__ dm,
                                              int* __restrict__ gmax) {
    int p = blockIdx.x * 256 + threadIdx.x;
    if (p == 0) gmax[0] = 0;
    float m = fmaxf(x[p], fmaxf(x[p + NPIX], x[p + 2 * NPIX]));
    dm[p] = 1.0f - m;
}

__device__ __forceinline__ int refl512(int t) {
    if (t < 0) t = -t;
    if (t > 511) t = 1022 - t;
    return t;
}

__global__ __launch_bounds__(256) void k_minrow(const float* __restrict__ dm, float* __restrict__ tmp) {
    int p = blockIdx.x * 256 + threadIdx.x;
    int i = p >> 9, j = p & 511;
    float m = 1e30f;
    #pragma unroll
    for (int d = -7; d <= 7; d++) m = fminf(m, dm[(i << 9) + refl512(j + d)]);
    tmp[p] = m;
}

__global__ __launch_bounds__(256) void k_mincol_max(const float* __restrict__ tmp, float* __restrict__ dark,
                                                    int* __restrict__ gmax) {
    int p = blockIdx.x * 256 + threadIdx.x;
    int i = p >> 9, j = p & 511;
    float m = 1e30f;
    #pragma unroll
    for (int d = -7; d <= 7; d++) m = fminf(m, tmp[(refl512(i + d) << 9) + j]);
    dark[p] = m;
    __shared__ float red[256];
    int tid = threadIdx.x;
    red[tid] = m;
    __syncthreads();
    for (int s = 128; s > 0; s >>= 1) {
        if (tid < s) red[tid] = fmaxf(red[tid], red[tid + s]);
        __syncthreads();
    }
    if (tid == 0) atomicMax(gmax, __float_as_int(red[0]));
}

// ---------------------------------------------------------------- prep helpers (device)
__device__ __forceinline__ void prep_one(const float* __restrict__ w, unsigned short* __restrict__ h,
                                         unsigned short* __restrict__ l, int N, int K, int cshift, int idx) {
    if (idx >= N * K) return;
    int n = idx / K, kord = idx - n * K;
    int ksrc = kord;
    if (cshift) {
        int dydx = kord >> cshift, c = kord & ((1 << cshift) - 1);
        ksrc = c * 4 + dydx;
    }
    float v = w[n * K + ksrc];
    unsigned short hb = f2bf(v);
    h[idx] = hb;
    if (l) l[idx] = f2bf(v - bf2f(hb));
}

__device__ __forceinline__ void bfft_one(int idx,
                                         unsigned short* __restrict__ BfH, unsigned short* __restrict__ BfL,
                                         unsigned short* __restrict__ BfcH, unsigned short* __restrict__ BfcL,
                                         unsigned short* __restrict__ BicH, unsigned short* __restrict__ BicL,
                                         unsigned short* __restrict__ BirH, unsigned short* __restrict__ BirL,
                                         float* __restrict__ zbias) {
    if (idx < 256) zbias[idx] = 0.f;
    const float w0 = 2.f * PI_F / 128.f;
    float v;
    unsigned short *H, *L;
    int off;
    if (idx < 32768) {                     // Bf [256][128]
        int n = idx >> 7, k = idx & 127;
        int t = n & 127, r = (t * k) & 127;
        float s_, c_; sincosf(w0 * r, &s_, &c_);
        v = (n < 128) ? c_ : -s_;
        H = BfH; L = BfL; off = idx;
    } else if (idx < 98304) {              // Bfc [256][256], PAIRED rows: n even = re(t=n/2), n odd = im(t=n/2)
        int i = idx - 32768;
        int n = i >> 8, j = i & 255;
        int t = n >> 1, r = (t * (j & 127)) & 127;
        float s_, c_; sincosf(w0 * r, &s_, &c_);
        bool isre = !(n & 1);
        v = isre ? ((j < 128) ? c_ : s_) : ((j < 128) ? -s_ : c_);
        H = BfcH; L = BfcL; off = i;
    } else if (idx < 163840) {             // Bic [256][256]
        int i = idx - 98304;
        int n = i >> 8, j = i & 255;
        int t = n & 127, r = (t * (j & 127)) & 127;
        float s_, c_; sincosf(w0 * r, &s_, &c_);
        v = ((n < 128) ? ((j < 128) ? c_ : -s_) : ((j < 128) ? s_ : c_)) * (1.f / 128.f);
        H = BicH; L = BicL; off = i;
    } else if (idx < 184320) {             // Bir [128][160]
        int i = idx - 163840;
        int col = i / 160, j = i - col * 160;
        if (j == 0) v = 1.f / 128.f;
        else if (j < 64)  { int r = (j * col) & 127; float s_, c_; sincosf(w0 * r, &s_, &c_); v = 2.f * c_ / 128.f; }
        else if (j == 64) v = (col & 1) ? -1.f / 128.f : 1.f / 128.f;
        else if (j >= 66 && j <= 128) { int k = j - 65; int r = (k * col) & 127; float s_, c_; sincosf(w0 * r, &s_, &c_); v = -2.f * s_ / 128.f; }
        else v = 0.f;
        H = BirH; L = BirL; off = i;
    } else return;
    unsigned short hb = f2bf(v);
    H[off] = hb;
    L[off] = f2bf(v - bf2f(hb));
}

// ---------------------------------------------------------------- merged prep kernel (weights + DFT matrices + composed Wc)
__global__ __launch_bounds__(256) void k_prep(
    const float* __restrict__ w_d1, unsigned short* __restrict__ d1h, unsigned short* __restrict__ d1l,
    const float* __restrict__ w_d2, unsigned short* __restrict__ d2h, unsigned short* __restrict__ d2l,
    const float* __restrict__ w_a1, unsigned short* __restrict__ a1h, unsigned short* __restrict__ a1l,
    const float* __restrict__ w_a2, unsigned short* __restrict__ a2h, unsigned short* __restrict__ a2l,
    const float* __restrict__ w_s1, unsigned short* __restrict__ s1h,
    const float* __restrict__ w_s2, unsigned short* __restrict__ s2h,
    const float* __restrict__ w_u1, unsigned short* __restrict__ u1h,
    const float* __restrict__ w_u3, unsigned short* __restrict__ u3h,
    const float* __restrict__ w_u4, unsigned short* __restrict__ u4h,
    unsigned short* __restrict__ BfH, unsigned short* __restrict__ BfL,
    unsigned short* __restrict__ BfcH, unsigned short* __restrict__ BfcL,
    unsigned short* __restrict__ BicH, unsigned short* __restrict__ BicL,
    unsigned short* __restrict__ BirH, unsigned short* __restrict__ BirL,
    float* __restrict__ zbias,
    const float* __restrict__ w2, const float* __restrict__ b2,
    const float* __restrict__ w3, const float* __restrict__ b3,
    const float* __restrict__ wu2, const float* __restrict__ bu2,
    float* __restrict__ Wc, float* __restrict__ bc,
    float* __restrict__ W2c, float* __restrict__ b2c) {
    int b = blockIdx.x, tid = threadIdx.x;
    if (b < 128)       prep_one(w_d1, d1h, d1l, 128, 256, 6, b * 256 + tid);
    else if (b < 640)  prep_one(w_d2, d2h, d2l, 256, 512, 7, (b - 128) * 256 + tid);
    else if (b < 896)  prep_one(w_a1, a1h, a1l, 256, 256, 0, (b - 640) * 256 + tid);
    else if (b < 1152) prep_one(w_a2, a2h, a2l, 256, 256, 0, (b - 896) * 256 + tid);
    else if (b < 1408) prep_one(w_s1, s1h, nullptr, 256, 256, 0, (b - 1152) * 256 + tid);
    else if (b < 1664) prep_one(w_s2, s2h, nullptr, 256, 256, 0, (b - 1408) * 256 + tid);
    else if (b < 1792) prep_one(w_u1, u1h, nullptr, 128, 256, 0, (b - 1664) * 256 + tid);
    else if (b < 1920) prep_one(w_u3, u3h, nullptr, 128, 256, 0, (b - 1792) * 256 + tid);
    else if (b < 1952) prep_one(w_u4, u4h, nullptr, 64, 128, 0, (b - 1920) * 256 + tid);
    else if (b < 2672) bfft_one((b - 1952) * 256 + tid, BfH, BfL, BfcH, BfcL, BicH, BicL, BirH, BirL, zbias);
    else {
        // composed weights (threads 0..127)
        __shared__ float sWc[3 * 128];
        if (tid < 128) {
            int j = tid;
            for (int r = 0; r < 3; r++) {
                float s = 0.f;
                for (int o = 0; o < 64; o++) s += w3[r * 64 + o] * w2[o * 128 + j];
                sWc[r * 128 + j] = s;
                Wc[r * 128 + j] = s;
            }
            if (j < 3) {
                float s = b3[j];
                for (int o = 0; o < 64; o++) s += w3[j * 64 + o] * b2[o];
                bc[j] = s;
            }
        }
        __syncthreads();
        if (tid < 128) {
            int j = tid;
            for (int r = 0; r < 3; r++) {
                float s = 0.f;
                for (int o = 0; o < 64; o++) s += sWc[r * 128 + o] * wu2[o * 128 + j];
                W2c[r * 128 + j] = s;
            }
            if (j < 3) {
                float s = 0.f;
                for (int o = 0; o < 64; o++) s += sWc[j * 128 + o] * bu2[o];
                b2c[j] = s;
            }
        }
    }
}

// ---------------------------------------------------------------- x_f = e2(e1(x)), written in d1's s2d [kord][m2] layout
// kord = dydx*64 + c ; m2 = i*256 + j ; source pixel (2i+dy, 2j+dx)
__global__ __launch_bounds__(256) void k_ef2(const float* __restrict__ x,
                                             const float* __restrict__ w1, const float* __restrict__ b1,
                                             const float* __restrict__ w2, const float* __restrict__ b2,
                                             float* __restrict__ out) {
    __shared__ float sw1[24], sb1[8], sw2[512], sb2[64];
    int tid = threadIdx.x;
    if (tid < 24) sw1[tid] = w1[tid];
    if (tid < 8)  sb1[tid] = b1[tid];
    if (tid < 64) sb2[tid] = b2[tid];
    if (tid < 256) { sw2[tid] = w2[tid]; sw2[tid + 256] = w2[tid + 256]; }
    __syncthreads();
    int bid = blockIdx.x;            // 1024 = 4 quadrants x 256 blocks
    int dydx = bid >> 8;
    int m2 = (bid & 255) * 256 + tid;
    int i = m2 >> 8, j = m2 & 255;
    int dy = dydx >> 1, dx = dydx & 1;
    int p5 = (2 * i + dy) * 512 + 2 * j + dx;
    float x0 = x[p5], x1 = x[p5 + NPIX], x2 = x[p5 + 2 * NPIX];
    float h[8];
    #pragma unroll
    for (int r = 0; r < 8; r++)
        h[r] = sw1[r * 3] * x0 + sw1[r * 3 + 1] * x1 + sw1[r * 3 + 2] * x2 + sb1[r];
    #pragma unroll 1
    for (int o = 0; o < 64; o++) {
        float acc = sb2[o];
        #pragma unroll
        for (int r = 0; r < 8; r++) acc += sw2[o * 8 + r] * h[r];
        out[(size_t)(dydx * 64 + o) * 65536 + m2] = acc;
    }
}

// ---------------------------------------------------------------- channels-first MFMA GEMM
// C[n][m] (or TSTORE: C[m][n]) = sum_k B[n][k] * A(k, m) + bias[n]
// AMODE 0: A[k][m] row-major [K][M] ; 1: s2d gather ; 3: A[m][K] ; 7: F2 read from F1T ; 8: I2 read from I1T
// EPI 0: normal store ; 1: amp-pair (sqrt(re^2+im^2) via shfl_xor, paired Bfc rows) ; 2: z-build (a*e^{ia} -> Z planes)
template<int AMODE, int SPLIT, int LRELU, int TSTORE, int EPI>
__global__ __launch_bounds__(256) void k_mmcf(const float* __restrict__ Asrc,
                                              const unsigned short* __restrict__ Bh,
                                              const unsigned short* __restrict__ Bl,
                                              const float* __restrict__ bias, float* __restrict__ C,
                                              int M, int N, int K, int cshift, int wshift, int srcW) {
    __shared__ unsigned short AhS[128 * 40];
    __shared__ unsigned short BhS[64 * 40];
    __shared__ unsigned short AlS[SPLIT ? 128 * 40 : 8];
    __shared__ unsigned short BlS[SPLIT ? 64 * 40 : 8];
    int tid = threadIdx.x;
    int m0 = blockIdx.x * 128;
    int n0 = blockIdx.y * 64;
    int wave = tid >> 6, lane = tid & 63;
    int wm = (wave >> 1) * 64, wn = (wave & 1) * 32;
    int l15 = lane & 15, quad = lane >> 4;
    int lk = quad * 8, lk4 = quad * 4;
    fx4 acc[4][2];
    #pragma unroll
    for (int a = 0; a < 4; a++)
        #pragma unroll
        for (int b = 0; b < 2; b++)
            acc[a][b] = (fx4){0.f, 0.f, 0.f, 0.f};

    int mm = tid & 127;
    int kpb = tid >> 7;          // 0/1
    int gm = m0 + mm;
    int oj = 0, oi = 0, cA = 0, kfA = 0, tauA = 0;
    size_t abase = 0;
    if (AMODE == 1) { oj = gm & ((1 << wshift) - 1); oi = gm >> wshift; }
    if (AMODE == 3) abase = (size_t)gm * K;
    if (AMODE == 7) { cA = gm / 65; kfA = gm - cA * 65; }
    if (AMODE == 8) { cA = gm >> 7; tauA = gm & 127; }

    for (int kb = 0; kb < K; kb += 32) {
        #pragma unroll
        for (int t = 0; t < 8; t++) {
            int kp = kpb * 8 + t;
            int k0 = kb + kp * 2;
            float a0, a1;
            if (AMODE == 0) {
                a0 = Asrc[(size_t)k0 * M + gm];
                a1 = Asrc[(size_t)(k0 + 1) * M + gm];
            } else if (AMODE == 1) {
                int c = k0 & ((1 << cshift) - 1);
                int dydx = k0 >> cshift;
                int dy = dydx >> 1, dx = dydx & 1;
                size_t pix = (size_t)(2 * oi + dy) * srcW + (2 * oj + dx);
                size_t plane = (size_t)srcW * srcW;
                a0 = Asrc[(size_t)c * plane + pix];
                a1 = Asrc[(size_t)(c + 1) * plane + pix];
            } else if (AMODE == 3) {
                a0 = Asrc[abase + k0];
                a1 = Asrc[abase + k0 + 1];
            } else if (AMODE == 7) {
                int t0 = k0 & 127, half = k0 >> 7;
                size_t ad = (size_t)(cA * 128 + t0) * 256 + half * 128 + kfA;
                a0 = Asrc[ad];
                a1 = Asrc[ad + 256];
            } else {                       // AMODE 8
                int j0 = k0, j1 = k0 + 1;
                int kf0 = (j0 < 65) ? j0 : ((j0 < 130) ? j0 - 65 : 0);
                int hf0 = (j0 >= 65 && j0 < 130) ? 1 : 0;
                int kf1 = (j1 < 65) ? j1 : ((j1 < 130) ? j1 - 65 : 0);
                int hf1 = (j1 >= 65 && j1 < 130) ? 1 : 0;
                a0 = Asrc[(size_t)(cA * 65 + kf0) * 256 + hf0 * 128 + tauA];
                a1 = Asrc[(size_t)(cA * 65 + kf1) * 256 + hf1 * 128 + tauA];
            }
            unsigned short h0 = f2bf(a0), h1 = f2bf(a1);
            *(unsigned*)(void*)&AhS[mm * 40 + kp * 2] = ((unsigned)h1 << 16) | (unsigned)h0;
            if (SPLIT) {
                unsigned short l0 = f2bf(a0 - bf2f(h0)), l1 = f2bf(a1 - bf2f(h1));
                *(unsigned*)(void*)&AlS[mm * 40 + kp * 2] = ((unsigned)l1 << 16) | (unsigned)l0;
            }
        }
        {
            int n = tid >> 2, seg = tid & 3;
            size_t gb = (size_t)(n0 + n) * K + kb + seg * 8;
            *(sh8*)(void*)&BhS[n * 40 + seg * 8] = *(const sh8*)(const void*)&Bh[gb];
            if (SPLIT) *(sh8*)(void*)&BlS[n * 40 + seg * 8] = *(const sh8*)(const void*)&Bl[gb];
        }
        __syncthreads();
        sh8 af[4], bf[2], afl[4], bfl[2];
        #pragma unroll
        for (int mt = 0; mt < 4; mt++) {
            af[mt] = *(const sh8*)(const void*)&AhS[(wm + mt * 16 + l15) * 40 + lk];
            if (SPLIT) afl[mt] = *(const sh8*)(const void*)&AlS[(wm + mt * 16 + l15) * 40 + lk];
        }
        #pragma unroll
        for (int nt = 0; nt < 2; nt++) {
            bf[nt] = *(const sh8*)(const void*)&BhS[(wn + nt * 16 + l15) * 40 + lk];
            if (SPLIT) bfl[nt] = *(const sh8*)(const void*)&BlS[(wn + nt * 16 + l15) * 40 + lk];
        }
        #pragma unroll
        for (int mt = 0; mt < 4; mt++)
            #pragma unroll
            for (int nt = 0; nt < 2; nt++) {
                acc[mt][nt] = __builtin_amdgcn_mfma_f32_16x16x32_bf16(af[mt], bf[nt], acc[mt][nt], 0, 0, 0);
                if (SPLIT) {
                    acc[mt][nt] = __builtin_amdgcn_mfma_f32_16x16x32_bf16(af[mt], bfl[nt], acc[mt][nt], 0, 0, 0);
                    acc[mt][nt] = __builtin_amdgcn_mfma_f32_16x16x32_bf16(afl[mt], bf[nt], acc[mt][nt], 0, 0, 0);
                }
            }
        __syncthreads();
    }
    #pragma unroll
    for (int nt = 0; nt < 2; nt++) {
        int n = n0 + wn + nt * 16 + l15;
        float bs = (EPI == 1) ? 0.f : bias[n];
        #pragma unroll
        for (int mt = 0; mt < 4; mt++) {
            int mbase = m0 + wm + mt * 16 + lk4;
            if (EPI == 1) {
                // paired re/im rows: n even = re(t=n/2), n odd = im(t=n/2). amp -> ampb[(c*128+t)*65+kf]
                int t = n >> 1;
                #pragma unroll
                for (int r = 0; r < 4; r++) {
                    float q = acc[mt][nt][r];
                    float other = __shfl_xor(q, 1, 64);
                    if (!(n & 1)) {
                        float amp = sqrtf(q * q + other * other);
                        int m = mbase + r;
                        int c = m / 65, kf = m - c * 65;
                        C[(size_t)(c * 128 + t) * 65 + kf] = amp;
                    }
                }
            } else if (EPI == 2) {
                // z-build: a = acc + bias; Z[t*16640 + n*65 + kf] = a*cos(a); +2129920 for a*sin(a)
                #pragma unroll
                for (int r = 0; r < 4; r++) {
                    float a = acc[mt][nt][r] + bs;
                    float s_, c_;
                    sincosf(a, &s_, &c_);
                    int m = mbase + r;
                    int t = m / 65, kf = m - t * 65;
                    size_t ad = (size_t)t * 16640 + n * 65 + kf;
                    C[ad] = a * c_;
                    C[2129920 + ad] = a * s_;
                }
            } else if (TSTORE) {
                #pragma unroll
                for (int r = 0; r < 4; r++) {
                    float q = acc[mt][nt][r] + bs;
                    if (LRELU) q = (q < 0.f) ? 0.1f * q : q;
                    C[(size_t)(mbase + r) * N + n] = q;
                }
            } else {
                float4 v;
                float* vp = (float*)&v;
                #pragma unroll
                for (int r = 0; r < 4; r++) {
                    float q = acc[mt][nt][r] + bs;
                    if (LRELU) q = (q < 0.f) ? 0.1f * q : q;
                    vp[r] = q;
                }
                *(float4*)&C[(size_t)n * M + mbase] = v;
            }
        }
    }
}

// ---------------------------------------------------------------- h3s = W2c @ g1 + b2c  (3ch @128^2)
__global__ __launch_bounds__(256) void k_h3s(const float* __restrict__ g1, const float* __restrict__ W2c,
                                             const float* __restrict__ b2c, float* __restrict__ h3s) {
    __shared__ float wa[384], bs[3];
    int tid = threadIdx.x;
    if (tid < 256) wa[tid] = W2c[tid];
    if (tid < 128) wa[256 + tid] = W2c[256 + tid];
    if (tid < 3) bs[tid] = b2c[tid];
    __syncthreads();
    int q = blockIdx.x * 256 + tid;
    float a0 = bs[0], a1 = bs[1], a2 = bs[2];
    #pragma unroll 4
    for (int c = 0; c < 128; c++) {
        float v = g1[(size_t)c * 16384 + q];
        a0 += wa[c] * v;
        a1 += wa[128 + c] * v;
        a2 += wa[256 + c] * v;
    }
    h3s[q] = a0; h3s[16384 + q] = a1; h3s[32768 + q] = a2;
}

// ---------------------------------------------------------------- channels-first bilinear x2 resize
__global__ __launch_bounds__(256) void k_resize2(const float* __restrict__ src, float* __restrict__ dst,
                                                 int C, int H) {
    int W2 = 2 * H;
    size_t idx = (size_t)blockIdx.x * 256 + threadIdx.x;
    size_t plane = (size_t)W2 * W2;
    if (idx >= (size_t)C * plane) return;
    int c = (int)(idx / plane);
    int rem = (int)(idx - (size_t)c * plane);
    int i = rem / W2, j = rem - i * W2;
    int ky = i >> 1, ylo, yhi; float wyl, wyh;
    if ((i & 1) == 0) { ylo = ky - 1; yhi = ky; wyl = .25f; wyh = .75f; if (ylo < 0) { ylo = 0; wyl = 0.f; wyh = 1.f; } }
    else              { ylo = ky; yhi = ky + 1; wyl = .75f; wyh = .25f; if (yhi > H - 1) { yhi = H - 1; wyh = 0.f; wyl = 1.f; } }
    int kx = j >> 1, xlo, xhi; float wxl, wxh;
    if ((j & 1) == 0) { xlo = kx - 1; xhi = kx; wxl = .25f; wxh = .75f; if (xlo < 0) { xlo = 0; wxl = 0.f; wxh = 1.f; } }
    else              { xlo = kx; xhi = kx + 1; wxl = .75f; wxh = .25f; if (xhi > H - 1) { xhi = H - 1; wxh = 0.f; wxl = 1.f; } }
    const float* p = src + (size_t)c * H * H;
    dst[idx] = wyl * (wxl * p[(size_t)ylo * H + xlo] + wxh * p[(size_t)ylo * H + xhi]) +
               wyh * (wxl * p[(size_t)yhi * H + xlo] + wxh * p[(size_t)yhi * H + xhi]);
}

// ---------------------------------------------------------------- final fused stage @512^2
__global__ __launch_bounds__(256) void k_final(const float* __restrict__ x,
                                               const float* __restrict__ dark, const int* __restrict__ gmax,
                                               const float* __restrict__ wcf1, const float* __restrict__ bcf1,
                                               const float* __restrict__ Wc, const float* __restrict__ bc,
                                               const float* __restrict__ g4, const float* __restrict__ h3,
                                               float* __restrict__ out) {
    __shared__ float dimt[32], w1[192], b1[64], wb[192], bcs[3];
    int tid = threadIdx.x;
    if (tid < 32) dimt[tid] = powf(10000.f, (float)(2 * (tid >> 1)) / 32.f);
    if (tid < 192) w1[tid] = wcf1[tid];
    if (tid < 64) b1[tid] = bcf1[tid];
    if (tid < 192) { int r = tid / 64, c = tid - (tid / 64) * 64; wb[tid] = Wc[r * 128 + 64 + c]; }
    if (tid < 3) bcs[tid] = bc[tid];
    __syncthreads();
    int p = blockIdx.x * 256 + tid;
    int i = p >> 9, j = p & 511;
    const float scale = 2.f * PI_F;
    float inv511 = scale / (511.f + 1e-6f);
    float xe = (float)j * inv511, ye = (float)i * inv511;
    float gm = __int_as_float(gmax[0]);
    float ze = dark[p] / (gm + 1e-6f) * scale;
    float x0 = x[p], x1 = x[p + NPIX], x2 = x[p + 2 * NPIX];

    int ky = i >> 1, ylo, yhi; float wyl, wyh;
    if ((i & 1) == 0) { ylo = ky - 1; yhi = ky; wyl = .25f; wyh = .75f; if (ylo < 0) { ylo = 0; wyl = 0.f; wyh = 1.f; } }
    else              { ylo = ky; yhi = ky + 1; wyl = .75f; wyh = .25f; if (yhi > 255) { yhi = 255; wyh = 0.f; wyl = 1.f; } }
    int kx = j >> 1, xlo, xhi; float wxl, wxh;
    if ((j & 1) == 0) { xlo = kx - 1; xhi = kx; wxl = .25f; wxh = .75f; if (xlo < 0) { xlo = 0; wxl = 0.f; wxh = 1.f; } }
    else              { xlo = kx; xhi = kx + 1; wxl = .75f; wxh = .25f; if (xhi > 255) { xhi = 255; wxh = 0.f; wxl = 1.f; } }
    int s00 = ylo * 256 + xlo, s01 = ylo * 256 + xhi, s10 = yhi * 256 + xlo, s11 = yhi * 256 + xhi;
    float w00 = wyl * wxl, w01 = wyl * wxh, w10 = wyh * wxl, w11 = wyh * wxh;

    float a0 = 0.f, a1 = 0.f, a2 = 0.f;
    #pragma unroll 1
    for (int c = 0; c < 64; c++) {
        float e = (c < 16) ? xe / dimt[c] : (c < 32) ? ye / dimt[c - 16] : ze / dimt[c - 32];
        float sn, cs;
        __sincosf(e, &sn, &cs);
        float pos = ((c & 1) == 0) ? sn : cs;
        float ape = pos + w1[c * 3] * x0 + w1[c * 3 + 1] * x1 + w1[c * 3 + 2] * x2 + b1[c];
        const float* gp = g4 + (size_t)c * 65536;
        float gv = w00 * gp[s00] + w01 * gp[s01] + w10 * gp[s10] + w11 * gp[s11];
        float s = gv * ape;
        a0 += wb[c] * s; a1 += wb[64 + c] * s; a2 += wb[128 + c] * s;
    }
    float f0 = w00 * h3[s00] + w01 * h3[s01] + w10 * h3[s10] + w11 * h3[s11];
    const float* h1 = h3 + 65536;
    float f1 = w00 * h1[s00] + w01 * h1[s01] + w10 * h1[s10] + w11 * h1[s11];
    const float* h2 = h3 + 131072;
    float f2 = w00 * h2[s00] + w01 * h2[s01] + w10 * h2[s10] + w11 * h2[s11];
    out[p]            = a0 + f0 + bcs[0] + x0;
    out[NPIX + p]     = a1 + f1 + bcs[1] + x1;
    out[2 * NPIX + p] = a2 + f2 + bcs[2] + x2;
}

// ================================================================ launcher
extern "C" void kernel_launch(void* const* d_in, const int* in_sizes, int n_in,
                              void* d_out, int out_size, void* d_ws, size_t ws_size,
                              hipStream_t stream) {
    const float* x      = (const float*)d_in[0];
    const float* w_cf1  = (const float*)d_in[1];  const float* b_cf1 = (const float*)d_in[2];
    const float* w_e1   = (const float*)d_in[3];  const float* b_e1  = (const float*)d_in[4];
    const float* w_e2   = (const float*)d_in[5];  const float* b_e2  = (const float*)d_in[6];
    const float* w_d1   = (const float*)d_in[7];  const float* b_d1  = (const float*)d_in[8];
    const float* w_d2   = (const float*)d_in[9];  const float* b_d2  = (const float*)d_in[10];
    // 11..14: pha branch is dead code in the reference
    const float* w_amp1 = (const float*)d_in[15]; const float* b_amp1 = (const float*)d_in[16];
    const float* w_amp2 = (const float*)d_in[17]; const float* b_amp2 = (const float*)d_in[18];
    const float* w_sp1  = (const float*)d_in[19]; const float* b_sp1  = (const float*)d_in[20];
    const float* w_sp2  = (const float*)d_in[21]; const float* b_sp2  = (const float*)d_in[22];
    const float* w_u1   = (const float*)d_in[23]; const float* b_u1   = (const float*)d_in[24];
    const float* w_u2   = (const float*)d_in[25]; const float* b_u2   = (const float*)d_in[26];
    const float* w_u3   = (const float*)d_in[27]; const float* b_u3   = (const float*)d_in[28];
    const float* w_u4   = (const float*)d_in[29]; const float* b_u4   = (const float*)d_in[30];
    const float* w_cf2  = (const float*)d_in[31]; const float* b_cf2  = (const float*)d_in[32];
    const float* w_cf3  = (const float*)d_in[33]; const float* b_cf3  = (const float*)d_in[34];
    float* out = (float*)d_out;

    char* ws = (char*)d_ws;
    constexpr size_t MiB = 1ull << 20;
    float*  dark   = (float*)(ws + 0 * MiB);
    float*  tmp    = (float*)(ws + 1 * MiB);
    int*    gmax   = (int*)  (ws + 2 * MiB);
    float*  Wc     = (float*)(ws + 2 * MiB + 1024);
    float*  bc     = (float*)(ws + 2 * MiB + 2560);
    float*  W2c    = (float*)(ws + 2 * MiB + 4096);
    float*  b2c    = (float*)(ws + 2 * MiB + 5632);
    float*  xfs    = (float*)(ws + 3 * MiB);     // 64 MiB [3,67)  s2d-layout [kord][m2]
    float*  xd1    = (float*)(ws + 67 * MiB);    // [67,99)
    float*  xd2    = (float*)(ws + 99 * MiB);    // [99,115) live until sp1
    float*  F1T    = (float*)(ws + 115 * MiB);   // 32    [115,147)
    float*  ampb   = (float*)(ws + 164 * MiB);   // 8.125 [164,172.125)
    float*  A1     = (float*)(ws + 173 * MiB);   // 8.125 [173,181.125)
    float*  Zbuf   = (float*)(ws + 115 * MiB);   // 16.25 (F1T dead after F2)
    float*  I1T    = (float*)(ws + 132 * MiB);   // 16.25 [132,149)
    float*  I2T    = (float*)(ws + 149 * MiB);   // 16    [149,165)
    float*  g1out  = (float*)(ws + 3 * MiB);     // 8 MiB [3,11) (xfs dead after d1)
    float*  h3s    = (float*)(ws + 11 * MiB);    // [11,11.2)
    float*  h3     = (float*)(ws + 27 * MiB);    // [27,27.75)
    float*  s1     = (float*)(ws + 31 * MiB);    // [31,47)
    float*  s2     = (float*)(ws + 47 * MiB);    // [47,63)
    float*  g3out  = (float*)(ws + 63 * MiB);    // [63,71) (xd1 dead)
    float*  g4out  = (float*)(ws + 71 * MiB);    // [71,87)
    float*  g4s    = (float*)(ws + 87 * MiB);    // [87,91)
    unsigned short* wb16 = (unsigned short*)(ws + 192 * MiB);
    unsigned short* d1h = wb16 + 0,       * d1l = wb16 + 32768;
    unsigned short* d2h = wb16 + 65536,   * d2l = wb16 + 196608;
    unsigned short* a1h = wb16 + 327680,  * a1l = wb16 + 393216;
    unsigned short* a2h = wb16 + 458752,  * a2l = wb16 + 524288;
    unsigned short* s1h = wb16 + 589824;
    unsigned short* s2h = wb16 + 655360;
    unsigned short* u1h = wb16 + 720896;
    unsigned short* u3h = wb16 + 753664;
    unsigned short* u4h = wb16 + 1155072;
    unsigned short* BfH = wb16 + 786432,  * BfL = wb16 + 819200;
    unsigned short* BfcH = wb16 + 851968, * BfcL = wb16 + 917504;
    unsigned short* BicH = wb16 + 983040, * BicL = wb16 + 1048576;
    unsigned short* BirH = wb16 + 1114112,* BirL = wb16 + 1134592;
    float* zbias = (float*)(ws + 195 * MiB + 512 * 1024);

    // 1) dark channel + gmax ; merged prep (weights + DFT matrices + composed Wc)
    k_minc<<<1024, 256, 0, stream>>>(x, dark, gmax);
    k_minrow<<<1024, 256, 0, stream>>>(dark, tmp);
    k_mincol_max<<<1024, 256, 0, stream>>>(tmp, dark, gmax);
    k_prep<<<2673, 256, 0, stream>>>(
        w_d1, d1h, d1l, w_d2, d2h, d2l, w_amp1, a1h, a1l, w_amp2, a2h, a2l,
        w_sp1, s1h, w_sp2, s2h, w_u1, u1h, w_u3, u3h, w_u4, u4h,
        BfH, BfL, BfcH, BfcL, BicH, BicL, BirH, BirL, zbias,
        w_cf2, b_cf2, w_cf3, b_cf3, w_u2, b_u2, Wc, bc, W2c, b2c);

    // 2) e1/e2 in s2d layout ; d1 coalesced AMODE 0 ; d2 AMODE 1
    k_ef2<<<1024, 256, 0, stream>>>(x, w_e1, b_e1, w_e2, b_e2, xfs);
    k_mmcf<0, 1, 0, 0, 0><<<dim3(512, 2), 256, 0, stream>>>(xfs, d1h, d1l, b_d1, xd1, 65536, 128, 256, 0, 0, 0);
    k_mmcf<1, 1, 0, 0, 0><<<dim3(128, 4), 256, 0, stream>>>(xd1, d2h, d2l, b_d2, xd2, 16384, 256, 512, 7, 7, 256);

    // 3) FFT section as MFMA GEMMs (TSTORE chain; amp fused into F2, zbuild into amp2)
    k_mmcf<3, 1, 0, 1, 0><<<dim3(256, 4), 256, 0, stream>>>(xd2, BfH, BfL, zbias, F1T, 32768, 256, 128, 0, 0, 0);
    k_mmcf<7, 1, 0, 0, 1><<<dim3(130, 4), 256, 0, stream>>>(F1T, BfcH, BfcL, zbias, ampb, 16640, 256, 256, 0, 0, 0);
    k_mmcf<0, 1, 1, 0, 0><<<dim3(65, 4), 256, 0, stream>>>(ampb, a1h, a1l, b_amp1, A1, 8320, 256, 256, 0, 0, 0);
    k_mmcf<0, 1, 0, 0, 2><<<dim3(65, 4), 256, 0, stream>>>(A1, a2h, a2l, b_amp2, Zbuf, 8320, 256, 256, 0, 0, 0);
    k_mmcf<0, 1, 0, 1, 0><<<dim3(130, 4), 256, 0, stream>>>(Zbuf, BicH, BicL, zbias, I1T, 16640, 256, 256, 0, 0, 0);
    k_mmcf<8, 1, 0, 1, 0><<<dim3(256, 2), 256, 0, stream>>>(I1T, BirH, BirL, zbias, I2T, 32768, 128, 160, 0, 0, 0);

    // 4) four path: u1 (coalesced) ; h3s ; resize 3ch
    k_mmcf<0, 0, 0, 0, 0><<<dim3(128, 2), 256, 0, stream>>>(I2T, u1h, nullptr, b_u1, g1out, 16384, 128, 256, 0, 0, 0);
    k_h3s<<<64, 256, 0, stream>>>(g1out, W2c, b2c, h3s);
    k_resize2<<<768, 256, 0, stream>>>(h3s, h3, 3, 128);

    // 5) spat path
    k_mmcf<0, 0, 1, 0, 0><<<dim3(128, 4), 256, 0, stream>>>(xd2, s1h, nullptr, b_sp1, s1, 16384, 256, 256, 0, 0, 0);
    k_mmcf<0, 0, 0, 0, 0><<<dim3(128, 4), 256, 0, stream>>>(s1, s2h, nullptr, b_sp2, s2, 16384, 256, 256, 0, 0, 0);
    k_mmcf<0, 0, 0, 0, 0><<<dim3(128, 2), 256, 0, stream>>>(s2, u3h, nullptr, b_u3, g3out, 16384, 128, 256, 0, 0, 0);
    k_mmcf<0, 0, 0, 0, 0><<<dim3(128, 1), 256, 0, stream>>>(g3out, u4h, nullptr, b_u4, g4s, 16384, 64, 128, 0, 0, 0);
    k_resize2<<<16384, 256, 0, stream>>>(g4s, g4out, 64, 128);

    // 6) final fused stage
    k_final<<<1024, 256, 0, stream>>>(x, dark, gmax, w_cf1, b_cf1, Wc, bc, g4out, h3, out);
}

// Round 13
// 492.520 us; speedup vs baseline: 1.0574x; 1.0574x over previous
//
#include <hip/hip_runtime.h>
#include <math.h>

#define PI_F 3.14159265358979323846f
#define NPIX 262144   // 512*512

typedef __attribute__((ext_vector_type(8))) short sh8;
typedef __attribute__((ext_vector_type(4))) float fx4;

__device__ __forceinline__ unsigned short f2bf(float v) {
    unsigned u = __float_as_uint(v);
    return (unsigned short)((u + 0x7FFFu + ((u >> 16) & 1)) >> 16);
}
__device__ __forceinline__ float bf2f(unsigned short h) {
    return __uint_as_float((unsigned)h << 16);
}

// ---------------------------------------------------------------- dark channel
__global__ __launch_bounds__(256) void k_minc(const float* __restrict__ x, float* __restrict__ dm,
                                              int* __restrict__ gmax) {
    int p = blockIdx.x * 256 + threadIdx.x;
    if (p == 0) gmax[0] = 0;
    float m = fmaxf(x[p], fmaxf(x[p + NPIX], x[p + 2 * NPIX]));
    dm[p] = 1.0f - m;
}

__device__ __forceinline__ int refl512(int t) {
    if (t < 0) t = -t;
    if (t > 511) t = 1022 - t;
    return t;
}

__global__ __launch_bounds__(256) void k_minrow(const float* __restrict__ dm, float* __restrict__ tmp) {
    int p = blockIdx.x * 256 + threadIdx.x;
    int i = p >> 9, j = p & 511;
    float m = 1e30f;
    #pragma unroll
    for (int d = -7; d <= 7; d++) m = fminf(m, dm[(i << 9) + refl512(j + d)]);
    tmp[p] = m;
}

__global__ __launch_bounds__(256) void k_mincol_max(const float* __restrict__ tmp, float* __restrict__ dark,
                                                    int* __restrict__ gmax) {
    int p = blockIdx.x * 256 + threadIdx.x;
    int i = p >> 9, j = p & 511;
    float m = 1e30f;
    #pragma unroll
    for (int d = -7; d <= 7; d++) m = fminf(m, tmp[(refl512(i + d) << 9) + j]);
    dark[p] = m;
    __shared__ float red[256];
    int tid = threadIdx.x;
    red[tid] = m;
    __syncthreads();
    for (int s = 128; s > 0; s >>= 1) {
        if (tid < s) red[tid] = fmaxf(red[tid], red[tid + s]);
        __syncthreads();
    }
    if (tid == 0) atomicMax(gmax, __float_as_int(red[0]));
}

// ---------------------------------------------------------------- prep helpers (device)
__device__ __forceinline__ void prep_one(const float* __restrict__ w, unsigned short* __restrict__ h,
                                         unsigned short* __restrict__ l, int N, int K, int cshift, int idx) {
    if (idx >= N * K) return;
    int n = idx / K, kord = idx - n * K;
    int ksrc = kord;
    if (cshift) {
        int dydx = kord >> cshift, c = kord & ((1 << cshift) - 1);
        ksrc = c * 4 + dydx;
    }
    float v = w[n * K + ksrc];
    unsigned short hb = f2bf(v);
    h[idx] = hb;
    if (l) l[idx] = f2bf(v - bf2f(hb));
}

__device__ __forceinline__ void bfft_one(int idx,
                                         unsigned short* __restrict__ BfH, unsigned short* __restrict__ BfL,
                                         unsigned short* __restrict__ BfcH, unsigned short* __restrict__ BfcL,
                                         unsigned short* __restrict__ BicH, unsigned short* __restrict__ BicL,
                                         unsigned short* __restrict__ BirH, unsigned short* __restrict__ BirL,
                                         float* __restrict__ zbias) {
    if (idx < 256) zbias[idx] = 0.f;
    const float w0 = 2.f * PI_F / 128.f;
    float v;
    unsigned short *H, *L;
    int off;
    if (idx < 32768) {                     // Bf [256][128]
        int n = idx >> 7, k = idx & 127;
        int t = n & 127, r = (t * k) & 127;
        float s_, c_; sincosf(w0 * r, &s_, &c_);
        v = (n < 128) ? c_ : -s_;
        H = BfH; L = BfL; off = idx;
    } else if (idx < 98304) {              // Bfc [256][256]  (R11 unpaired rows)
        int i = idx - 32768;
        int n = i >> 8, j = i & 255;
        int t = n & 127, r = (t * (j & 127)) & 127;
        float s_, c_; sincosf(w0 * r, &s_, &c_);
        v = (n < 128) ? ((j < 128) ? c_ : s_) : ((j < 128) ? -s_ : c_);
        H = BfcH; L = BfcL; off = i;
    } else if (idx < 163840) {             // Bic [256][256]
        int i = idx - 98304;
        int n = i >> 8, j = i & 255;
        int t = n & 127, r = (t * (j & 127)) & 127;
        float s_, c_; sincosf(w0 * r, &s_, &c_);
        v = ((n < 128) ? ((j < 128) ? c_ : -s_) : ((j < 128) ? s_ : c_)) * (1.f / 128.f);
        H = BicH; L = BicL; off = i;
    } else if (idx < 184320) {             // Bir [128][160]
        int i = idx - 163840;
        int col = i / 160, j = i - col * 160;
        if (j == 0) v = 1.f / 128.f;
        else if (j < 64)  { int r = (j * col) & 127; float s_, c_; sincosf(w0 * r, &s_, &c_); v = 2.f * c_ / 128.f; }
        else if (j == 64) v = (col & 1) ? -1.f / 128.f : 1.f / 128.f;
        else if (j >= 66 && j <= 128) { int k = j - 65; int r = (k * col) & 127; float s_, c_; sincosf(w0 * r, &s_, &c_); v = -2.f * s_ / 128.f; }
        else v = 0.f;
        H = BirH; L = BirL; off = i;
    } else return;
    unsigned short hb = f2bf(v);
    H[off] = hb;
    L[off] = f2bf(v - bf2f(hb));
}

// ---------------------------------------------------------------- merged prep kernel
__global__ __launch_bounds__(256) void k_prep(
    const float* __restrict__ w_d1, unsigned short* __restrict__ d1h, unsigned short* __restrict__ d1l,
    const float* __restrict__ w_d2, unsigned short* __restrict__ d2h, unsigned short* __restrict__ d2l,
    const float* __restrict__ w_a1, unsigned short* __restrict__ a1h, unsigned short* __restrict__ a1l,
    const float* __restrict__ w_a2, unsigned short* __restrict__ a2h, unsigned short* __restrict__ a2l,
    const float* __restrict__ w_s1, unsigned short* __restrict__ s1h,
    const float* __restrict__ w_s2, unsigned short* __restrict__ s2h,
    const float* __restrict__ w_u3, const float* __restrict__ w_u4, unsigned short* __restrict__ u43h,
    const float* __restrict__ b_u3, const float* __restrict__ b_u4, float* __restrict__ b43,
    unsigned short* __restrict__ BfH, unsigned short* __restrict__ BfL,
    unsigned short* __restrict__ BfcH, unsigned short* __restrict__ BfcL,
    unsigned short* __restrict__ BicH, unsigned short* __restrict__ BicL,
    unsigned short* __restrict__ BirH, unsigned short* __restrict__ BirL,
    float* __restrict__ zbias,
    const float* __restrict__ w2, const float* __restrict__ b2,
    const float* __restrict__ w3, const float* __restrict__ b3,
    const float* __restrict__ wu2, const float* __restrict__ bu2,
    const float* __restrict__ wu1, const float* __restrict__ bu1,
    float* __restrict__ Wc, float* __restrict__ bc,
    float* __restrict__ W21c, float* __restrict__ b21c) {
    int b = blockIdx.x, tid = threadIdx.x;
    if (b < 128)       prep_one(w_d1, d1h, d1l, 128, 256, 6, b * 256 + tid);
    else if (b < 640)  prep_one(w_d2, d2h, d2l, 256, 512, 7, (b - 128) * 256 + tid);
    else if (b < 896)  prep_one(w_a1, a1h, a1l, 256, 256, 0, (b - 640) * 256 + tid);
    else if (b < 1152) prep_one(w_a2, a2h, a2l, 256, 256, 0, (b - 896) * 256 + tid);
    else if (b < 1408) prep_one(w_s1, s1h, nullptr, 256, 256, 0, (b - 1152) * 256 + tid);
    else if (b < 1664) prep_one(w_s2, s2h, nullptr, 256, 256, 0, (b - 1408) * 256 + tid);
    else if (b < 2384) bfft_one((b - 1664) * 256 + tid, BfH, BfL, BfcH, BfcL, BicH, BicL, BirH, BirL, zbias);
    else if (b < 2448) {
        // u43 = w_u4 (64x128) @ w_u3 (128x256), bf16
        int idx = (b - 2384) * 256 + tid;     // [0,16384)
        int n = idx >> 8, j = idx & 255;
        float s = 0.f;
        for (int o = 0; o < 128; o++) s += w_u4[n * 128 + o] * w_u3[o * 256 + j];
        u43h[idx] = f2bf(s);
    } else {
        // composed cf weights + W21c chain + biases
        __shared__ float sWc[384], sW2c[384];
        if (tid < 128) {
            int j = tid;
            for (int r = 0; r < 3; r++) {
                float s = 0.f;
                for (int o = 0; o < 64; o++) s += w3[r * 64 + o] * w2[o * 128 + j];
                sWc[r * 128 + j] = s;
                Wc[r * 128 + j] = s;
            }
            if (j < 3) {
                float s = b3[j];
                for (int o = 0; o < 64; o++) s += w3[j * 64 + o] * b2[o];
                bc[j] = s;
            }
        }
        if (tid >= 128 && tid < 192) {
            int n = tid - 128;
            float s = b_u4[n];
            for (int o = 0; o < 128; o++) s += w_u4[n * 128 + o] * b_u3[o];
            b43[n] = s;
        }
        __syncthreads();
        if (tid < 128) {
            int j = tid;
            for (int r = 0; r < 3; r++) {
                float s = 0.f;
                for (int o = 0; o < 64; o++) s += sWc[r * 128 + o] * wu2[o * 128 + j];
                sW2c[r * 128 + j] = s;
            }
        }
        __syncthreads();
        if (tid < 256) {
            int j = tid;
            for (int r = 0; r < 3; r++) {
                float s = 0.f;
                for (int o = 0; o < 128; o++) s += sW2c[r * 128 + o] * wu1[o * 256 + j];
                W21c[r * 256 + j] = s;
            }
        }
        if (tid < 3) {
            float s = 0.f;
            for (int o = 0; o < 128; o++) s += sW2c[tid * 128 + o] * bu1[o];
            for (int o = 0; o < 64; o++)  s += sWc[tid * 128 + o] * bu2[o];
            b21c[tid] = s;
        }
    }
}

// ---------------------------------------------------------------- x_f = e2(e1(x)), written in d1's s2d [kord][m2] layout
__global__ __launch_bounds__(256) void k_ef2(const float* __restrict__ x,
                                             const float* __restrict__ w1, const float* __restrict__ b1,
                                             const float* __restrict__ w2, const float* __restrict__ b2,
                                             float* __restrict__ out) {
    __shared__ float sw1[24], sb1[8], sw2[512], sb2[64];
    int tid = threadIdx.x;
    if (tid < 24) sw1[tid] = w1[tid];
    if (tid < 8)  sb1[tid] = b1[tid];
    if (tid < 64) sb2[tid] = b2[tid];
    if (tid < 256) { sw2[tid] = w2[tid]; sw2[tid + 256] = w2[tid + 256]; }
    __syncthreads();
    int bid = blockIdx.x;
    int dydx = bid >> 8;
    int m2 = (bid & 255) * 256 + tid;
    int i = m2 >> 8, j = m2 & 255;
    int dy = dydx >> 1, dx = dydx & 1;
    int p5 = (2 * i + dy) * 512 + 2 * j + dx;
    float x0 = x[p5], x1 = x[p5 + NPIX], x2 = x[p5 + 2 * NPIX];
    float h[8];
    #pragma unroll
    for (int r = 0; r < 8; r++)
        h[r] = sw1[r * 3] * x0 + sw1[r * 3 + 1] * x1 + sw1[r * 3 + 2] * x2 + sb1[r];
    #pragma unroll 1
    for (int o = 0; o < 64; o++) {
        float acc = sb2[o];
        #pragma unroll
        for (int r = 0; r < 8; r++) acc += sw2[o * 8 + r] * h[r];
        out[(size_t)(dydx * 64 + o) * 65536 + m2] = acc;
    }
}

// ---------------------------------------------------------------- channels-first MFMA GEMM (R11-verified)
// C[n][m] (or TSTORE: C[m][n]) = sum_k B[n][k] * A(k, m) + bias[n]
// AMODE 0: A[k][m] [K][M] ; 1: s2d gather ; 3: A[m][K] ; 7: F2 read from F1T ; 8: I2 read from I1T
template<int AMODE, int SPLIT, int LRELU, int TSTORE>
__global__ __launch_bounds__(256) void k_mmcf(const float* __restrict__ Asrc,
                                              const unsigned short* __restrict__ Bh,
                                              const unsigned short* __restrict__ Bl,
                                              const float* __restrict__ bias, float* __restrict__ C,
                                              int M, int N, int K, int cshift, int wshift, int srcW) {
    __shared__ unsigned short AhS[128 * 40];
    __shared__ unsigned short BhS[64 * 40];
    __shared__ unsigned short AlS[SPLIT ? 128 * 40 : 8];
    __shared__ unsigned short BlS[SPLIT ? 64 * 40 : 8];
    int tid = threadIdx.x;
    int m0 = blockIdx.x * 128;
    int n0 = blockIdx.y * 64;
    int wave = tid >> 6, lane = tid & 63;
    int wm = (wave >> 1) * 64, wn = (wave & 1) * 32;
    int l15 = lane & 15, quad = lane >> 4;
    int lk = quad * 8, lk4 = quad * 4;
    fx4 acc[4][2];
    #pragma unroll
    for (int a = 0; a < 4; a++)
        #pragma unroll
        for (int b = 0; b < 2; b++)
            acc[a][b] = (fx4){0.f, 0.f, 0.f, 0.f};

    int mm = tid & 127;
    int kpb = tid >> 7;
    int gm = m0 + mm;
    int oj = 0, oi = 0, cA = 0, kfA = 0, tauA = 0;
    size_t abase = 0;
    if (AMODE == 1) { oj = gm & ((1 << wshift) - 1); oi = gm >> wshift; }
    if (AMODE == 3) abase = (size_t)gm * K;
    if (AMODE == 7) { cA = gm / 65; kfA = gm - cA * 65; }
    if (AMODE == 8) { cA = gm >> 7; tauA = gm & 127; }

    for (int kb = 0; kb < K; kb += 32) {
        #pragma unroll
        for (int t = 0; t < 8; t++) {
            int kp = kpb * 8 + t;
            int k0 = kb + kp * 2;
            float a0, a1;
            if (AMODE == 0) {
                a0 = Asrc[(size_t)k0 * M + gm];
                a1 = Asrc[(size_t)(k0 + 1) * M + gm];
            } else if (AMODE == 1) {
                int c = k0 & ((1 << cshift) - 1);
                int dydx = k0 >> cshift;
                int dy = dydx >> 1, dx = dydx & 1;
                size_t pix = (size_t)(2 * oi + dy) * srcW + (2 * oj + dx);
                size_t plane = (size_t)srcW * srcW;
                a0 = Asrc[(size_t)c * plane + pix];
                a1 = Asrc[(size_t)(c + 1) * plane + pix];
            } else if (AMODE == 3) {
                a0 = Asrc[abase + k0];
                a1 = Asrc[abase + k0 + 1];
            } else if (AMODE == 7) {
                int t0 = k0 & 127, half = k0 >> 7;
                size_t ad = (size_t)(cA * 128 + t0) * 256 + half * 128 + kfA;
                a0 = Asrc[ad];
                a1 = Asrc[ad + 256];
            } else {                       // AMODE 8
                int j0 = k0, j1 = k0 + 1;
                int kf0 = (j0 < 65) ? j0 : ((j0 < 130) ? j0 - 65 : 0);
                int hf0 = (j0 >= 65 && j0 < 130) ? 1 : 0;
                int kf1 = (j1 < 65) ? j1 : ((j1 < 130) ? j1 - 65 : 0);
                int hf1 = (j1 >= 65 && j1 < 130) ? 1 : 0;
                a0 = Asrc[(size_t)(cA * 65 + kf0) * 256 + hf0 * 128 + tauA];
                a1 = Asrc[(size_t)(cA * 65 + kf1) * 256 + hf1 * 128 + tauA];
            }
            unsigned short h0 = f2bf(a0), h1 = f2bf(a1);
            *(unsigned*)(void*)&AhS[mm * 40 + kp * 2] = ((unsigned)h1 << 16) | (unsigned)h0;
            if (SPLIT) {
                unsigned short l0 = f2bf(a0 - bf2f(h0)), l1 = f2bf(a1 - bf2f(h1));
                *(unsigned*)(void*)&AlS[mm * 40 + kp * 2] = ((unsigned)l1 << 16) | (unsigned)l0;
            }
        }
        {
            int n = tid >> 2, seg = tid & 3;
            size_t gb = (size_t)(n0 + n) * K + kb + seg * 8;
            *(sh8*)(void*)&BhS[n * 40 + seg * 8] = *(const sh8*)(const void*)&Bh[gb];
            if (SPLIT) *(sh8*)(void*)&BlS[n * 40 + seg * 8] = *(const sh8*)(const void*)&Bl[gb];
        }
        __syncthreads();
        sh8 af[4], bf[2], afl[4], bfl[2];
        #pragma unroll
        for (int mt = 0; mt < 4; mt++) {
            af[mt] = *(const sh8*)(const void*)&AhS[(wm + mt * 16 + l15) * 40 + lk];
            if (SPLIT) afl[mt] = *(const sh8*)(const void*)&AlS[(wm + mt * 16 + l15) * 40 + lk];
        }
        #pragma unroll
        for (int nt = 0; nt < 2; nt++) {
            bf[nt] = *(const sh8*)(const void*)&BhS[(wn + nt * 16 + l15) * 40 + lk];
            if (SPLIT) bfl[nt] = *(const sh8*)(const void*)&BlS[(wn + nt * 16 + l15) * 40 + lk];
        }
        #pragma unroll
        for (int mt = 0; mt < 4; mt++)
            #pragma unroll
            for (int nt = 0; nt < 2; nt++) {
                acc[mt][nt] = __builtin_amdgcn_mfma_f32_16x16x32_bf16(af[mt], bf[nt], acc[mt][nt], 0, 0, 0);
                if (SPLIT) {
                    acc[mt][nt] = __builtin_amdgcn_mfma_f32_16x16x32_bf16(af[mt], bfl[nt], acc[mt][nt], 0, 0, 0);
                    acc[mt][nt] = __builtin_amdgcn_mfma_f32_16x16x32_bf16(afl[mt], bf[nt], acc[mt][nt], 0, 0, 0);
                }
            }
        __syncthreads();
    }
    #pragma unroll
    for (int nt = 0; nt < 2; nt++) {
        int n = n0 + wn + nt * 16 + l15;
        float bs = bias[n];
        #pragma unroll
        for (int mt = 0; mt < 4; mt++) {
            int mbase = m0 + wm + mt * 16 + lk4;
            if (TSTORE) {
                #pragma unroll
                for (int r = 0; r < 4; r++) {
                    float q = acc[mt][nt][r] + bs;
                    if (LRELU) q = (q < 0.f) ? 0.1f * q : q;
                    C[(size_t)(mbase + r) * N + n] = q;
                }
            } else {
                float4 v;
                float* vp = (float*)&v;
                #pragma unroll
                for (int r = 0; r < 4; r++) {
                    float q = acc[mt][nt][r] + bs;
                    if (LRELU) q = (q < 0.f) ? 0.1f * q : q;
                    vp[r] = q;
                }
                *(float4*)&C[(size_t)n * M + mbase] = v;
            }
        }
    }
}

// ---------------------------------------------------------------- amp = sqrt(re^2+im^2), layout -> [c][t][kf]
__global__ __launch_bounds__(128) void k_ampc(const float* __restrict__ F2C, float* __restrict__ ampb) {
    int bid = blockIdx.x;          // c*128 + t
    int kf = threadIdx.x;
    if (kf >= 65) return;
    int c = bid >> 7, t = bid & 127;
    size_t m = (size_t)c * 65 + kf;
    float re = F2C[(size_t)t * 16640 + m];
    float im = F2C[(size_t)(t + 128) * 16640 + m];
    ampb[(size_t)bid * 65 + kf] = sqrtf(re * re + im * im);
}

// ---------------------------------------------------------------- z = a*(cos a, sin a) -> stacked [t][(c,kf)] planes
__global__ __launch_bounds__(128) void k_zbuild(const float* __restrict__ A2, float* __restrict__ Z) {
    int bid = blockIdx.x;          // c*128 + t
    int kf = threadIdx.x;
    if (kf >= 65) return;
    int c = bid >> 7, t = bid & 127;
    float a = A2[(size_t)bid * 65 + kf];
    float s_, c_;
    sincosf(a, &s_, &c_);
    size_t m = (size_t)c * 65 + kf;
    Z[(size_t)t * 16640 + m] = a * c_;
    Z[2129920 + (size_t)t * 16640 + m] = a * s_;
}

// ---------------------------------------------------------------- h3s = W21c @ I2T + b21c  (3ch @128^2, K=256)
__global__ __launch_bounds__(256) void k_h3s(const float* __restrict__ I2T, const float* __restrict__ W21c,
                                             const float* __restrict__ b21c, float* __restrict__ h3s) {
    __shared__ float wa[768], bs[3];
    int tid = threadIdx.x;
    for (int i = tid; i < 768; i += 256) wa[i] = W21c[i];
    if (tid < 3) bs[tid] = b21c[tid];
    __syncthreads();
    int q = blockIdx.x * 256 + tid;
    float a0 = bs[0], a1 = bs[1], a2 = bs[2];
    #pragma unroll 4
    for (int c = 0; c < 256; c++) {
        float v = I2T[(size_t)c * 16384 + q];
        a0 += wa[c] * v;
        a1 += wa[256 + c] * v;
        a2 += wa[512 + c] * v;
    }
    h3s[q] = a0; h3s[16384 + q] = a1; h3s[32768 + q] = a2;
}

// ---------------------------------------------------------------- channels-first bilinear x2 resize
__global__ __launch_bounds__(256) void k_resize2(const float* __restrict__ src, float* __restrict__ dst,
                                                 int C, int H) {
    int W2 = 2 * H;
    size_t idx = (size_t)blockIdx.x * 256 + threadIdx.x;
    size_t plane = (size_t)W2 * W2;
    if (idx >= (size_t)C * plane) return;
    int c = (int)(idx / plane);
    int rem = (int)(idx - (size_t)c * plane);
    int i = rem / W2, j = rem - i * W2;
    int ky = i >> 1, ylo, yhi; float wyl, wyh;
    if ((i & 1) == 0) { ylo = ky - 1; yhi = ky; wyl = .25f; wyh = .75f; if (ylo < 0) { ylo = 0; wyl = 0.f; wyh = 1.f; } }
    else              { ylo = ky; yhi = ky + 1; wyl = .75f; wyh = .25f; if (yhi > H - 1) { yhi = H - 1; wyh = 0.f; wyl = 1.f; } }
    int kx = j >> 1, xlo, xhi; float wxl, wxh;
    if ((j & 1) == 0) { xlo = kx - 1; xhi = kx; wxl = .25f; wxh = .75f; if (xlo < 0) { xlo = 0; wxl = 0.f; wxh = 1.f; } }
    else              { xlo = kx; xhi = kx + 1; wxl = .75f; wxh = .25f; if (xhi > H - 1) { xhi = H - 1; wxh = 0.f; wxl = 1.f; } }
    const float* p = src + (size_t)c * H * H;
    dst[idx] = wyl * (wxl * p[(size_t)ylo * H + xlo] + wxh * p[(size_t)ylo * H + xhi]) +
               wyh * (wxl * p[(size_t)yhi * H + xlo] + wxh * p[(size_t)yhi * H + xhi]);
}

// ---------------------------------------------------------------- final fused stage @512^2
__global__ __launch_bounds__(256) void k_final(const float* __restrict__ x,
                                               const float* __restrict__ dark, const int* __restrict__ gmax,
                                               const float* __restrict__ wcf1, const float* __restrict__ bcf1,
                                               const float* __restrict__ Wc, const float* __restrict__ bc,
                                               const float* __restrict__ g4, const float* __restrict__ h3,
                                               float* __restrict__ out) {
    __shared__ float dimt[32], w1[192], b1[64], wb[192], bcs[3];
    int tid = threadIdx.x;
    if (tid < 32) dimt[tid] = powf(10000.f, (float)(2 * (tid >> 1)) / 32.f);
    if (tid < 192) w1[tid] = wcf1[tid];
    if (tid < 64) b1[tid] = bcf1[tid];
    if (tid < 192) { int r = tid / 64, c = tid - (tid / 64) * 64; wb[tid] = Wc[r * 128 + 64 + c]; }
    if (tid < 3) bcs[tid] = bc[tid];
    __syncthreads();
    int p = blockIdx.x * 256 + tid;
    int i = p >> 9, j = p & 511;
    const float scale = 2.f * PI_F;
    float inv511 = scale / (511.f + 1e-6f);
    float xe = (float)j * inv511, ye = (float)i * inv511;
    float gm = __int_as_float(gmax[0]);
    float ze = dark[p] / (gm + 1e-6f) * scale;
    float x0 = x[p], x1 = x[p + NPIX], x2 = x[p + 2 * NPIX];

    int ky = i >> 1, ylo, yhi; float wyl, wyh;
    if ((i & 1) == 0) { ylo = ky - 1; yhi = ky; wyl = .25f; wyh = .75f; if (ylo < 0) { ylo = 0; wyl = 0.f; wyh = 1.f; } }
    else              { ylo = ky; yhi = ky + 1; wyl = .75f; wyh = .25f; if (yhi > 255) { yhi = 255; wyh = 0.f; wyl = 1.f; } }
    int kx = j >> 1, xlo, xhi; float wxl, wxh;
    if ((j & 1) == 0) { xlo = kx - 1; xhi = kx; wxl = .25f; wxh = .75f; if (xlo < 0) { xlo = 0; wxl = 0.f; wxh = 1.f; } }
    else              { xlo = kx; xhi = kx + 1; wxl = .75f; wxh = .25f; if (xhi > 255) { xhi = 255; wxh = 0.f; wxl = 1.f; } }
    int s00 = ylo * 256 + xlo, s01 = ylo * 256 + xhi, s10 = yhi * 256 + xlo, s11 = yhi * 256 + xhi;
    float w00 = wyl * wxl, w01 = wyl * wxh, w10 = wyh * wxl, w11 = wyh * wxh;

    float a0 = 0.f, a1 = 0.f, a2 = 0.f;
    #pragma unroll 1
    for (int c = 0; c < 64; c++) {
        float e = (c < 16) ? xe / dimt[c] : (c < 32) ? ye / dimt[c - 16] : ze / dimt[c - 32];
        float sn, cs;
        __sincosf(e, &sn, &cs);
        float pos = ((c & 1) == 0) ? sn : cs;
        float ape = pos + w1[c * 3] * x0 + w1[c * 3 + 1] * x1 + w1[c * 3 + 2] * x2 + b1[c];
        const float* gp = g4 + (size_t)c * 65536;
        float gv = w00 * gp[s00] + w01 * gp[s01] + w10 * gp[s10] + w11 * gp[s11];
        float s = gv * ape;
        a0 += wb[c] * s; a1 += wb[64 + c] * s; a2 += wb[128 + c] * s;
    }
    float f0 = w00 * h3[s00] + w01 * h3[s01] + w10 * h3[s10] + w11 * h3[s11];
    const float* h1 = h3 + 65536;
    float f1 = w00 * h1[s00] + w01 * h1[s01] + w10 * h1[s10] + w11 * h1[s11];
    const float* h2 = h3 + 131072;
    float f2 = w00 * h2[s00] + w01 * h2[s01] + w10 * h2[s10] + w11 * h2[s11];
    out[p]            = a0 + f0 + bcs[0] + x0;
    out[NPIX + p]     = a1 + f1 + bcs[1] + x1;
    out[2 * NPIX + p] = a2 + f2 + bcs[2] + x2;
}

// ================================================================ launcher
extern "C" void kernel_launch(void* const* d_in, const int* in_sizes, int n_in,
                              void* d_out, int out_size, void* d_ws, size_t ws_size,
                              hipStream_t stream) {
    const float* x      = (const float*)d_in[0];
    const float* w_cf1  = (const float*)d_in[1];  const float* b_cf1 = (const float*)d_in[2];
    const float* w_e1   = (const float*)d_in[3];  const float* b_e1  = (const float*)d_in[4];
    const float* w_e2   = (const float*)d_in[5];  const float* b_e2  = (const float*)d_in[6];
    const float* w_d1   = (const float*)d_in[7];  const float* b_d1  = (const float*)d_in[8];
    const float* w_d2   = (const float*)d_in[9];  const float* b_d2  = (const float*)d_in[10];
    // 11..14: pha branch is dead code in the reference
    const float* w_amp1 = (const float*)d_in[15]; const float* b_amp1 = (const float*)d_in[16];
    const float* w_amp2 = (const float*)d_in[17]; const float* b_amp2 = (const float*)d_in[18];
    const float* w_sp1  = (const float*)d_in[19]; const float* b_sp1  = (const float*)d_in[20];
    const float* w_sp2  = (const float*)d_in[21]; const float* b_sp2  = (const float*)d_in[22];
    const float* w_u1   = (const float*)d_in[23]; const float* b_u1   = (const float*)d_in[24];
    const float* w_u2   = (const float*)d_in[25]; const float* b_u2   = (const float*)d_in[26];
    const float* w_u3   = (const float*)d_in[27]; const float* b_u3   = (const float*)d_in[28];
    const float* w_u4   = (const float*)d_in[29]; const float* b_u4   = (const float*)d_in[30];
    const float* w_cf2  = (const float*)d_in[31]; const float* b_cf2  = (const float*)d_in[32];
    const float* w_cf3  = (const float*)d_in[33]; const float* b_cf3  = (const float*)d_in[34];
    float* out = (float*)d_out;

    char* ws = (char*)d_ws;
    constexpr size_t MiB = 1ull << 20;
    float*  dark   = (float*)(ws + 0 * MiB);
    float*  tmp    = (float*)(ws + 1 * MiB);
    int*    gmax   = (int*)  (ws + 2 * MiB);
    float*  Wc     = (float*)(ws + 2 * MiB + 1024);
    float*  bc     = (float*)(ws + 2 * MiB + 2560);
    float*  W21c   = (float*)(ws + 2 * MiB + 4096);   // 768 floats
    float*  b21c   = (float*)(ws + 2 * MiB + 7168);
    float*  b43    = (float*)(ws + 2 * MiB + 7424);   // 64 floats
    float*  xfs    = (float*)(ws + 3 * MiB);     // [3,67)  s2d-layout
    float*  xd1    = (float*)(ws + 67 * MiB);    // [67,99)
    float*  xd2    = (float*)(ws + 99 * MiB);    // [99,115)
    float*  F1T    = (float*)(ws + 115 * MiB);   // [115,147)
    float*  F2C    = (float*)(ws + 147 * MiB);   // [147,163.25)
    float*  ampb   = (float*)(ws + 164 * MiB);   // [164,172.125)
    float*  A1     = (float*)(ws + 173 * MiB);   // [173,181.125)
    float*  A2     = (float*)(ws + 182 * MiB);   // [182,190.125)
    float*  Zbuf   = (float*)(ws + 115 * MiB);   // (F1T dead after F2)
    float*  I1T    = (float*)(ws + 132 * MiB);   // [132,149)
    float*  I2T    = (float*)(ws + 149 * MiB);   // [149,165)
    float*  h3s    = (float*)(ws + 11 * MiB);    // [11,11.2)
    float*  h3     = (float*)(ws + 27 * MiB);    // [27,27.75)
    float*  s1     = (float*)(ws + 31 * MiB);    // [31,47)
    float*  s2     = (float*)(ws + 47 * MiB);    // [47,63)
    float*  g4out  = (float*)(ws + 71 * MiB);    // [71,87)
    float*  g4s    = (float*)(ws + 87 * MiB);    // [87,91)
    unsigned short* wb16 = (unsigned short*)(ws + 192 * MiB);
    unsigned short* d1h = wb16 + 0,       * d1l = wb16 + 32768;
    unsigned short* d2h = wb16 + 65536,   * d2l = wb16 + 196608;
    unsigned short* a1h = wb16 + 327680,  * a1l = wb16 + 393216;
    unsigned short* a2h = wb16 + 458752,  * a2l = wb16 + 524288;
    unsigned short* s1h = wb16 + 589824;
    unsigned short* s2h = wb16 + 655360;
    unsigned short* u43h = wb16 + 720896;          // 16384 shorts
    unsigned short* BfH = wb16 + 786432,  * BfL = wb16 + 819200;
    unsigned short* BfcH = wb16 + 851968, * BfcL = wb16 + 917504;
    unsigned short* BicH = wb16 + 983040, * BicL = wb16 + 1048576;
    unsigned short* BirH = wb16 + 1114112,* BirL = wb16 + 1134592;
    float* zbias = (float*)(ws + 195 * MiB + 512 * 1024);

    // 1) dark channel + gmax ; merged prep
    k_minc<<<1024, 256, 0, stream>>>(x, dark, gmax);
    k_minrow<<<1024, 256, 0, stream>>>(dark, tmp);
    k_mincol_max<<<1024, 256, 0, stream>>>(tmp, dark, gmax);
    k_prep<<<2449, 256, 0, stream>>>(
        w_d1, d1h, d1l, w_d2, d2h, d2l, w_amp1, a1h, a1l, w_amp2, a2h, a2l,
        w_sp1, s1h, w_sp2, s2h,
        w_u3, w_u4, u43h, b_u3, b_u4, b43,
        BfH, BfL, BfcH, BfcL, BicH, BicL, BirH, BirL, zbias,
        w_cf2, b_cf2, w_cf3, b_cf3, w_u2, b_u2, w_u1, b_u1, Wc, bc, W21c, b21c);

    // 2) e1/e2 in s2d layout ; d1 coalesced AMODE 0 ; d2 AMODE 1
    k_ef2<<<1024, 256, 0, stream>>>(x, w_e1, b_e1, w_e2, b_e2, xfs);
    k_mmcf<0, 1, 0, 0><<<dim3(512, 2), 256, 0, stream>>>(xfs, d1h, d1l, b_d1, xd1, 65536, 128, 256, 0, 0, 0);
    k_mmcf<1, 1, 0, 0><<<dim3(128, 4), 256, 0, stream>>>(xd1, d2h, d2l, b_d2, xd2, 16384, 256, 512, 7, 7, 256);

    // 3) FFT section as MFMA GEMMs (R11-verified form)
    k_mmcf<3, 1, 0, 1><<<dim3(256, 4), 256, 0, stream>>>(xd2, BfH, BfL, zbias, F1T, 32768, 256, 128, 0, 0, 0);
    k_mmcf<7, 1, 0, 0><<<dim3(130, 4), 256, 0, stream>>>(F1T, BfcH, BfcL, zbias, F2C, 16640, 256, 256, 0, 0, 0);
    k_ampc<<<32768, 128, 0, stream>>>(F2C, ampb);
    k_mmcf<0, 1, 1, 0><<<dim3(65, 4), 256, 0, stream>>>(ampb, a1h, a1l, b_amp1, A1, 8320, 256, 256, 0, 0, 0);
    k_mmcf<0, 1, 0, 0><<<dim3(65, 4), 256, 0, stream>>>(A1, a2h, a2l, b_amp2, A2, 8320, 256, 256, 0, 0, 0);
    k_zbuild<<<32768, 128, 0, stream>>>(A2, Zbuf);
    k_mmcf<0, 1, 0, 1><<<dim3(130, 4), 256, 0, stream>>>(Zbuf, BicH, BicL, zbias, I1T, 16640, 256, 256, 0, 0, 0);
    k_mmcf<8, 1, 0, 1><<<dim3(256, 2), 256, 0, stream>>>(I1T, BirH, BirL, zbias, I2T, 32768, 128, 160, 0, 0, 0);

    // 4) four path: h3s = W21c @ I2T directly (u1 composed away) ; resize 3ch
    k_h3s<<<64, 256, 0, stream>>>(I2T, W21c, b21c, h3s);
    k_resize2<<<768, 256, 0, stream>>>(h3s, h3, 3, 128);

    // 5) spat path: sp1, sp2, then composed u43 GEMM ; resize 64ch
    k_mmcf<0, 0, 1, 0><<<dim3(128, 4), 256, 0, stream>>>(xd2, s1h, nullptr, b_sp1, s1, 16384, 256, 256, 0, 0, 0);
    k_mmcf<0, 0, 0, 0><<<dim3(128, 4), 256, 0, stream>>>(s1, s2h, nullptr, b_sp2, s2, 16384, 256, 256, 0, 0, 0);
    k_mmcf<0, 0, 0, 0><<<dim3(128, 1), 256, 0, stream>>>(s2, u43h, nullptr, b43, g4s, 16384, 64, 256, 0, 0, 0);
    k_resize2<<<16384, 256, 0, stream>>>(g4s, g4out, 64, 128);

    // 6) final fused stage
    k_final<<<1024, 256, 0, stream>>>(x, dark, gmax, w_cf1, b_cf1, Wc, bc, g4out, h3, out);
}

// Round 14
// 465.045 us; speedup vs baseline: 1.1199x; 1.0591x over previous
//
#include <hip/hip_runtime.h>
#include <math.h>

#define PI_F 3.14159265358979323846f
#define NPIX 262144   // 512*512

typedef __attribute__((ext_vector_type(8))) short sh8;
typedef __attribute__((ext_vector_type(4))) float fx4;

__device__ __forceinline__ unsigned short f2bf(float v) {
    unsigned u = __float_as_uint(v);
    return (unsigned short)((u + 0x7FFFu + ((u >> 16) & 1)) >> 16);
}
__device__ __forceinline__ float bf2f(unsigned short h) {
    return __uint_as_float((unsigned)h << 16);
}

// ---------------------------------------------------------------- dark channel
__global__ __launch_bounds__(256) void k_minc(const float* __restrict__ x, float* __restrict__ dm,
                                              int* __restrict__ gmax) {
    int p = blockIdx.x * 256 + threadIdx.x;
    if (p == 0) gmax[0] = 0;
    float m = fmaxf(x[p], fmaxf(x[p + NPIX], x[p + 2 * NPIX]));
    dm[p] = 1.0f - m;
}

__device__ __forceinline__ int refl512(int t) {
    if (t < 0) t = -t;
    if (t > 511) t = 1022 - t;
    return t;
}

__global__ __launch_bounds__(256) void k_minrow(const float* __restrict__ dm, float* __restrict__ tmp) {
    int p = blockIdx.x * 256 + threadIdx.x;
    int i = p >> 9, j = p & 511;
    float m = 1e30f;
    #pragma unroll
    for (int d = -7; d <= 7; d++) m = fminf(m, dm[(i << 9) + refl512(j + d)]);
    tmp[p] = m;
}

__global__ __launch_bounds__(256) void k_mincol_max(const float* __restrict__ tmp, float* __restrict__ dark,
                                                    int* __restrict__ gmax) {
    int p = blockIdx.x * 256 + threadIdx.x;
    int i = p >> 9, j = p & 511;
    float m = 1e30f;
    #pragma unroll
    for (int d = -7; d <= 7; d++) m = fminf(m, tmp[(refl512(i + d) << 9) + j]);
    dark[p] = m;
    __shared__ float red[256];
    int tid = threadIdx.x;
    red[tid] = m;
    __syncthreads();
    for (int s = 128; s > 0; s >>= 1) {
        if (tid < s) red[tid] = fmaxf(red[tid], red[tid + s]);
        __syncthreads();
    }
    if (tid == 0) atomicMax(gmax, __float_as_int(red[0]));
}

// ---------------------------------------------------------------- prep helpers (device)
__device__ __forceinline__ void prep_one(const float* __restrict__ w, unsigned short* __restrict__ h,
                                         unsigned short* __restrict__ l, int N, int K, int cshift, int idx) {
    if (idx >= N * K) return;
    int n = idx / K, kord = idx - n * K;
    int ksrc = kord;
    if (cshift) {
        int dydx = kord >> cshift, c = kord & ((1 << cshift) - 1);
        ksrc = c * 4 + dydx;
    }
    float v = w[n * K + ksrc];
    unsigned short hb = f2bf(v);
    h[idx] = hb;
    if (l) l[idx] = f2bf(v - bf2f(hb));
}

__device__ __forceinline__ void bfft_one(int idx,
                                         unsigned short* __restrict__ BfH, unsigned short* __restrict__ BfL,
                                         unsigned short* __restrict__ BfcH, unsigned short* __restrict__ BfcL,
                                         unsigned short* __restrict__ BicH, unsigned short* __restrict__ BicL,
                                         unsigned short* __restrict__ BirH, unsigned short* __restrict__ BirL,
                                         float* __restrict__ zbias) {
    if (idx < 256) zbias[idx] = 0.f;
    const float w0 = 2.f * PI_F / 128.f;
    float v;
    unsigned short *H, *L;
    int off;
    if (idx < 32768) {                     // Bf [256][128]
        int n = idx >> 7, k = idx & 127;
        int t = n & 127, r = (t * k) & 127;
        float s_, c_; sincosf(w0 * r, &s_, &c_);
        v = (n < 128) ? c_ : -s_;
        H = BfH; L = BfL; off = idx;
    } else if (idx < 98304) {              // Bfc [256][256]
        int i = idx - 32768;
        int n = i >> 8, j = i & 255;
        int t = n & 127, r = (t * (j & 127)) & 127;
        float s_, c_; sincosf(w0 * r, &s_, &c_);
        v = (n < 128) ? ((j < 128) ? c_ : s_) : ((j < 128) ? -s_ : c_);
        H = BfcH; L = BfcL; off = i;
    } else if (idx < 163840) {             // Bic [256][256]
        int i = idx - 98304;
        int n = i >> 8, j = i & 255;
        int t = n & 127, r = (t * (j & 127)) & 127;
        float s_, c_; sincosf(w0 * r, &s_, &c_);
        v = ((n < 128) ? ((j < 128) ? c_ : -s_) : ((j < 128) ? s_ : c_)) * (1.f / 128.f);
        H = BicH; L = BicL; off = i;
    } else if (idx < 184320) {             // Bir [128][160]
        int i = idx - 163840;
        int col = i / 160, j = i - col * 160;
        if (j == 0) v = 1.f / 128.f;
        else if (j < 64)  { int r = (j * col) & 127; float s_, c_; sincosf(w0 * r, &s_, &c_); v = 2.f * c_ / 128.f; }
        else if (j == 64) v = (col & 1) ? -1.f / 128.f : 1.f / 128.f;
        else if (j >= 66 && j <= 128) { int k = j - 65; int r = (k * col) & 127; float s_, c_; sincosf(w0 * r, &s_, &c_); v = -2.f * s_ / 128.f; }
        else v = 0.f;
        H = BirH; L = BirL; off = i;
    } else return;
    unsigned short hb = f2bf(v);
    H[off] = hb;
    L[off] = f2bf(v - bf2f(hb));
}

// ---------------------------------------------------------------- merged prep kernel (unrolled reduction loops)
__global__ __launch_bounds__(256) void k_prep(
    const float* __restrict__ w_d1, unsigned short* __restrict__ d1h, unsigned short* __restrict__ d1l,
    const float* __restrict__ w_d2, unsigned short* __restrict__ d2h, unsigned short* __restrict__ d2l,
    const float* __restrict__ w_a1, unsigned short* __restrict__ a1h, unsigned short* __restrict__ a1l,
    const float* __restrict__ w_a2, unsigned short* __restrict__ a2h, unsigned short* __restrict__ a2l,
    const float* __restrict__ w_s1, unsigned short* __restrict__ s1h,
    const float* __restrict__ w_s2, unsigned short* __restrict__ s2h,
    const float* __restrict__ w_u3, const float* __restrict__ w_u4, unsigned short* __restrict__ u43h,
    const float* __restrict__ b_u3, const float* __restrict__ b_u4, float* __restrict__ b43,
    unsigned short* __restrict__ BfH, unsigned short* __restrict__ BfL,
    unsigned short* __restrict__ BfcH, unsigned short* __restrict__ BfcL,
    unsigned short* __restrict__ BicH, unsigned short* __restrict__ BicL,
    unsigned short* __restrict__ BirH, unsigned short* __restrict__ BirL,
    float* __restrict__ zbias,
    const float* __restrict__ w2, const float* __restrict__ b2,
    const float* __restrict__ w3, const float* __restrict__ b3,
    const float* __restrict__ wu2, const float* __restrict__ bu2,
    const float* __restrict__ wu1, const float* __restrict__ bu1,
    float* __restrict__ Wc, float* __restrict__ bc,
    float* __restrict__ W21c, float* __restrict__ b21c) {
    int b = blockIdx.x, tid = threadIdx.x;
    if (b < 128)       prep_one(w_d1, d1h, d1l, 128, 256, 6, b * 256 + tid);
    else if (b < 640)  prep_one(w_d2, d2h, d2l, 256, 512, 7, (b - 128) * 256 + tid);
    else if (b < 896)  prep_one(w_a1, a1h, a1l, 256, 256, 0, (b - 640) * 256 + tid);
    else if (b < 1152) prep_one(w_a2, a2h, a2l, 256, 256, 0, (b - 896) * 256 + tid);
    else if (b < 1408) prep_one(w_s1, s1h, nullptr, 256, 256, 0, (b - 1152) * 256 + tid);
    else if (b < 1664) prep_one(w_s2, s2h, nullptr, 256, 256, 0, (b - 1408) * 256 + tid);
    else if (b < 2384) bfft_one((b - 1664) * 256 + tid, BfH, BfL, BfcH, BfcL, BicH, BicL, BirH, BirL, zbias);
    else if (b < 2448) {
        // u43 = w_u4 (64x128) @ w_u3 (128x256), bf16
        int idx = (b - 2384) * 256 + tid;     // [0,16384)
        int n = idx >> 8, j = idx & 255;
        float s = 0.f;
        #pragma unroll 16
        for (int o = 0; o < 128; o++) s += w_u4[n * 128 + o] * w_u3[o * 256 + j];
        u43h[idx] = f2bf(s);
    } else {
        // composed cf weights + W21c chain + biases (unrolled so loads pipeline)
        __shared__ float sWc[384], sW2c[384];
        if (tid < 128) {
            int j = tid;
            for (int r = 0; r < 3; r++) {
                float s = 0.f;
                #pragma unroll 16
                for (int o = 0; o < 64; o++) s += w3[r * 64 + o] * w2[o * 128 + j];
                sWc[r * 128 + j] = s;
                Wc[r * 128 + j] = s;
            }
            if (j < 3) {
                float s = b3[j];
                #pragma unroll 16
                for (int o = 0; o < 64; o++) s += w3[j * 64 + o] * b2[o];
                bc[j] = s;
            }
        }
        if (tid >= 128 && tid < 192) {
            int n = tid - 128;
            float s = b_u4[n];
            #pragma unroll 16
            for (int o = 0; o < 128; o++) s += w_u4[n * 128 + o] * b_u3[o];
            b43[n] = s;
        }
        __syncthreads();
        if (tid < 128) {
            int j = tid;
            for (int r = 0; r < 3; r++) {
                float s = 0.f;
                #pragma unroll 16
                for (int o = 0; o < 64; o++) s += sWc[r * 128 + o] * wu2[o * 128 + j];
                sW2c[r * 128 + j] = s;
            }
        }
        __syncthreads();
        if (tid < 256) {
            int j = tid;
            for (int r = 0; r < 3; r++) {
                float s = 0.f;
                #pragma unroll 16
                for (int o = 0; o < 128; o++) s += sW2c[r * 128 + o] * wu1[o * 256 + j];
                W21c[r * 256 + j] = s;
            }
        }
        if (tid < 3) {
            float s = 0.f;
            #pragma unroll 16
            for (int o = 0; o < 128; o++) s += sW2c[tid * 128 + o] * bu1[o];
            #pragma unroll 16
            for (int o = 0; o < 64; o++)  s += sWc[tid * 128 + o] * bu2[o];
            b21c[tid] = s;
        }
    }
}

// ---------------------------------------------------------------- x_f = e2(e1(x)), written in d1's s2d [kord][m2] layout
__global__ __launch_bounds__(256) void k_ef2(const float* __restrict__ x,
                                             const float* __restrict__ w1, const float* __restrict__ b1,
                                             const float* __restrict__ w2, const float* __restrict__ b2,
                                             float* __restrict__ out) {
    __shared__ float sw1[24], sb1[8], sw2[512], sb2[64];
    int tid = threadIdx.x;
    if (tid < 24) sw1[tid] = w1[tid];
    if (tid < 8)  sb1[tid] = b1[tid];
    if (tid < 64) sb2[tid] = b2[tid];
    if (tid < 256) { sw2[tid] = w2[tid]; sw2[tid + 256] = w2[tid + 256]; }
    __syncthreads();
    int bid = blockIdx.x;
    int dydx = bid >> 8;
    int m2 = (bid & 255) * 256 + tid;
    int i = m2 >> 8, j = m2 & 255;
    int dy = dydx >> 1, dx = dydx & 1;
    int p5 = (2 * i + dy) * 512 + 2 * j + dx;
    float x0 = x[p5], x1 = x[p5 + NPIX], x2 = x[p5 + 2 * NPIX];
    float h[8];
    #pragma unroll
    for (int r = 0; r < 8; r++)
        h[r] = sw1[r * 3] * x0 + sw1[r * 3 + 1] * x1 + sw1[r * 3 + 2] * x2 + sb1[r];
    #pragma unroll 1
    for (int o = 0; o < 64; o++) {
        float acc = sb2[o];
        #pragma unroll
        for (int r = 0; r < 8; r++) acc += sw2[o * 8 + r] * h[r];
        out[(size_t)(dydx * 64 + o) * 65536 + m2] = acc;
    }
}

// ---------------------------------------------------------------- channels-first MFMA GEMM (R11-verified)
// C[n][m] (or TSTORE: C[m][n]) = sum_k B[n][k] * A(k, m) + bias[n]
// AMODE 0: A[k][m] [K][M] ; 1: s2d gather ; 3: A[m][K] ; 7: F2 read from F1T ; 8: I2 read from I1T
template<int AMODE, int SPLIT, int LRELU, int TSTORE>
__global__ __launch_bounds__(256) void k_mmcf(const float* __restrict__ Asrc,
                                              const unsigned short* __restrict__ Bh,
                                              const unsigned short* __restrict__ Bl,
                                              const float* __restrict__ bias, float* __restrict__ C,
                                              int M, int N, int K, int cshift, int wshift, int srcW) {
    __shared__ unsigned short AhS[128 * 40];
    __shared__ unsigned short BhS[64 * 40];
    __shared__ unsigned short AlS[SPLIT ? 128 * 40 : 8];
    __shared__ unsigned short BlS[SPLIT ? 64 * 40 : 8];
    int tid = threadIdx.x;
    int m0 = blockIdx.x * 128;
    int n0 = blockIdx.y * 64;
    int wave = tid >> 6, lane = tid & 63;
    int wm = (wave >> 1) * 64, wn = (wave & 1) * 32;
    int l15 = lane & 15, quad = lane >> 4;
    int lk = quad * 8, lk4 = quad * 4;
    fx4 acc[4][2];
    #pragma unroll
    for (int a = 0; a < 4; a++)
        #pragma unroll
        for (int b = 0; b < 2; b++)
            acc[a][b] = (fx4){0.f, 0.f, 0.f, 0.f};

    int mm = tid & 127;
    int kpb = tid >> 7;
    int gm = m0 + mm;
    int oj = 0, oi = 0, cA = 0, kfA = 0, tauA = 0;
    size_t abase = 0;
    if (AMODE == 1) { oj = gm & ((1 << wshift) - 1); oi = gm >> wshift; }
    if (AMODE == 3) abase = (size_t)gm * K;
    if (AMODE == 7) { cA = gm / 65; kfA = gm - cA * 65; }
    if (AMODE == 8) { cA = gm >> 7; tauA = gm & 127; }

    for (int kb = 0; kb < K; kb += 32) {
        #pragma unroll
        for (int t = 0; t < 8; t++) {
            int kp = kpb * 8 + t;
            int k0 = kb + kp * 2;
            float a0, a1;
            if (AMODE == 0) {
                a0 = Asrc[(size_t)k0 * M + gm];
                a1 = Asrc[(size_t)(k0 + 1) * M + gm];
            } else if (AMODE == 1) {
                int c = k0 & ((1 << cshift) - 1);
                int dydx = k0 >> cshift;
                int dy = dydx >> 1, dx = dydx & 1;
                size_t pix = (size_t)(2 * oi + dy) * srcW + (2 * oj + dx);
                size_t plane = (size_t)srcW * srcW;
                a0 = Asrc[(size_t)c * plane + pix];
                a1 = Asrc[(size_t)(c + 1) * plane + pix];
            } else if (AMODE == 3) {
                a0 = Asrc[abase + k0];
                a1 = Asrc[abase + k0 + 1];
            } else if (AMODE == 7) {
                int t0 = k0 & 127, half = k0 >> 7;
                size_t ad = (size_t)(cA * 128 + t0) * 256 + half * 128 + kfA;
                a0 = Asrc[ad];
                a1 = Asrc[ad + 256];
            } else {                       // AMODE 8
                int j0 = k0, j1 = k0 + 1;
                int kf0 = (j0 < 65) ? j0 : ((j0 < 130) ? j0 - 65 : 0);
                int hf0 = (j0 >= 65 && j0 < 130) ? 1 : 0;
                int kf1 = (j1 < 65) ? j1 : ((j1 < 130) ? j1 - 65 : 0);
                int hf1 = (j1 >= 65 && j1 < 130) ? 1 : 0;
                a0 = Asrc[(size_t)(cA * 65 + kf0) * 256 + hf0 * 128 + tauA];
                a1 = Asrc[(size_t)(cA * 65 + kf1) * 256 + hf1 * 128 + tauA];
            }
            unsigned short h0 = f2bf(a0), h1 = f2bf(a1);
            *(unsigned*)(void*)&AhS[mm * 40 + kp * 2] = ((unsigned)h1 << 16) | (unsigned)h0;
            if (SPLIT) {
                unsigned short l0 = f2bf(a0 - bf2f(h0)), l1 = f2bf(a1 - bf2f(h1));
                *(unsigned*)(void*)&AlS[mm * 40 + kp * 2] = ((unsigned)l1 << 16) | (unsigned)l0;
            }
        }
        {
            int n = tid >> 2, seg = tid & 3;
            size_t gb = (size_t)(n0 + n) * K + kb + seg * 8;
            *(sh8*)(void*)&BhS[n * 40 + seg * 8] = *(const sh8*)(const void*)&Bh[gb];
            if (SPLIT) *(sh8*)(void*)&BlS[n * 40 + seg * 8] = *(const sh8*)(const void*)&Bl[gb];
        }
        __syncthreads();
        sh8 af[4], bf[2], afl[4], bfl[2];
        #pragma unroll
        for (int mt = 0; mt < 4; mt++) {
            af[mt] = *(const sh8*)(const void*)&AhS[(wm + mt * 16 + l15) * 40 + lk];
            if (SPLIT) afl[mt] = *(const sh8*)(const void*)&AlS[(wm + mt * 16 + l15) * 40 + lk];
        }
        #pragma unroll
        for (int nt = 0; nt < 2; nt++) {
            bf[nt] = *(const sh8*)(const void*)&BhS[(wn + nt * 16 + l15) * 40 + lk];
            if (SPLIT) bfl[nt] = *(const sh8*)(const void*)&BlS[(wn + nt * 16 + l15) * 40 + lk];
        }
        #pragma unroll
        for (int mt = 0; mt < 4; mt++)
            #pragma unroll
            for (int nt = 0; nt < 2; nt++) {
                acc[mt][nt] = __builtin_amdgcn_mfma_f32_16x16x32_bf16(af[mt], bf[nt], acc[mt][nt], 0, 0, 0);
                if (SPLIT) {
                    acc[mt][nt] = __builtin_amdgcn_mfma_f32_16x16x32_bf16(af[mt], bfl[nt], acc[mt][nt], 0, 0, 0);
                    acc[mt][nt] = __builtin_amdgcn_mfma_f32_16x16x32_bf16(afl[mt], bf[nt], acc[mt][nt], 0, 0, 0);
                }
            }
        __syncthreads();
    }
    #pragma unroll
    for (int nt = 0; nt < 2; nt++) {
        int n = n0 + wn + nt * 16 + l15;
        float bs = bias[n];
        #pragma unroll
        for (int mt = 0; mt < 4; mt++) {
            int mbase = m0 + wm + mt * 16 + lk4;
            if (TSTORE) {
                #pragma unroll
                for (int r = 0; r < 4; r++) {
                    float q = acc[mt][nt][r] + bs;
                    if (LRELU) q = (q < 0.f) ? 0.1f * q : q;
                    C[(size_t)(mbase + r) * N + n] = q;
                }
            } else {
                float4 v;
                float* vp = (float*)&v;
                #pragma unroll
                for (int r = 0; r < 4; r++) {
                    float q = acc[mt][nt][r] + bs;
                    if (LRELU) q = (q < 0.f) ? 0.1f * q : q;
                    vp[r] = q;
                }
                *(float4*)&C[(size_t)n * M + mbase] = v;
            }
        }
    }
}

// ---------------------------------------------------------------- amp = sqrt(re^2+im^2), layout -> [c][t][kf]
__global__ __launch_bounds__(128) void k_ampc(const float* __restrict__ F2C, float* __restrict__ ampb) {
    int bid = blockIdx.x;          // c*128 + t
    int kf = threadIdx.x;
    if (kf >= 65) return;
    int c = bid >> 7, t = bid & 127;
    size_t m = (size_t)c * 65 + kf;
    float re = F2C[(size_t)t * 16640 + m];
    float im = F2C[(size_t)(t + 128) * 16640 + m];
    ampb[(size_t)bid * 65 + kf] = sqrtf(re * re + im * im);
}

// ---------------------------------------------------------------- z = a*(cos a, sin a) -> stacked [t][(c,kf)] planes
__global__ __launch_bounds__(128) void k_zbuild(const float* __restrict__ A2, float* __restrict__ Z) {
    int bid = blockIdx.x;          // c*128 + t
    int kf = threadIdx.x;
    if (kf >= 65) return;
    int c = bid >> 7, t = bid & 127;
    float a = A2[(size_t)bid * 65 + kf];
    float s_, c_;
    sincosf(a, &s_, &c_);
    size_t m = (size_t)c * 65 + kf;
    Z[(size_t)t * 16640 + m] = a * c_;
    Z[2129920 + (size_t)t * 16640 + m] = a * s_;
}

// ---------------------------------------------------------------- h3s = W21c @ I2T + b21c  (3ch @128^2, K=256)
__global__ __launch_bounds__(256) void k_h3s(const float* __restrict__ I2T, const float* __restrict__ W21c,
                                             const float* __restrict__ b21c, float* __restrict__ h3s) {
    __shared__ float wa[768], bs[3];
    int tid = threadIdx.x;
    for (int i = tid; i < 768; i += 256) wa[i] = W21c[i];
    if (tid < 3) bs[tid] = b21c[tid];
    __syncthreads();
    int q = blockIdx.x * 256 + tid;
    float a0 = bs[0], a1 = bs[1], a2 = bs[2];
    #pragma unroll 4
    for (int c = 0; c < 256; c++) {
        float v = I2T[(size_t)c * 16384 + q];
        a0 += wa[c] * v;
        a1 += wa[256 + c] * v;
        a2 += wa[512 + c] * v;
    }
    h3s[q] = a0; h3s[16384 + q] = a1; h3s[32768 + q] = a2;
}

// ---------------------------------------------------------------- channels-first bilinear x2 resize
__global__ __launch_bounds__(256) void k_resize2(const float* __restrict__ src, float* __restrict__ dst,
                                                 int C, int H) {
    int W2 = 2 * H;
    size_t idx = (size_t)blockIdx.x * 256 + threadIdx.x;
    size_t plane = (size_t)W2 * W2;
    if (idx >= (size_t)C * plane) return;
    int c = (int)(idx / plane);
    int rem = (int)(idx - (size_t)c * plane);
    int i = rem / W2, j = rem - i * W2;
    int ky = i >> 1, ylo, yhi; float wyl, wyh;
    if ((i & 1) == 0) { ylo = ky - 1; yhi = ky; wyl = .25f; wyh = .75f; if (ylo < 0) { ylo = 0; wyl = 0.f; wyh = 1.f; } }
    else              { ylo = ky; yhi = ky + 1; wyl = .75f; wyh = .25f; if (yhi > H - 1) { yhi = H - 1; wyh = 0.f; wyl = 1.f; } }
    int kx = j >> 1, xlo, xhi; float wxl, wxh;
    if ((j & 1) == 0) { xlo = kx - 1; xhi = kx; wxl = .25f; wxh = .75f; if (xlo < 0) { xlo = 0; wxl = 0.f; wxh = 1.f; } }
    else              { xlo = kx; xhi = kx + 1; wxl = .75f; wxh = .25f; if (xhi > H - 1) { xhi = H - 1; wxh = 0.f; wxl = 1.f; } }
    const float* p = src + (size_t)c * H * H;
    dst[idx] = wyl * (wxl * p[(size_t)ylo * H + xlo] + wxh * p[(size_t)ylo * H + xhi]) +
               wyh * (wxl * p[(size_t)yhi * H + xlo] + wxh * p[(size_t)yhi * H + xhi]);
}

// ---------------------------------------------------------------- final fused stage @512^2
__global__ __launch_bounds__(256) void k_final(const float* __restrict__ x,
                                               const float* __restrict__ dark, const int* __restrict__ gmax,
                                               const float* __restrict__ wcf1, const float* __restrict__ bcf1,
                                               const float* __restrict__ Wc, const float* __restrict__ bc,
                                               const float* __restrict__ g4, const float* __restrict__ h3,
                                               float* __restrict__ out) {
    __shared__ float dimt[32], w1[192], b1[64], wb[192], bcs[3];
    int tid = threadIdx.x;
    if (tid < 32) dimt[tid] = powf(10000.f, (float)(2 * (tid >> 1)) / 32.f);
    if (tid < 192) w1[tid] = wcf1[tid];
    if (tid < 64) b1[tid] = bcf1[tid];
    if (tid < 192) { int r = tid / 64, c = tid - (tid / 64) * 64; wb[tid] = Wc[r * 128 + 64 + c]; }
    if (tid < 3) bcs[tid] = bc[tid];
    __syncthreads();
    int p = blockIdx.x * 256 + tid;
    int i = p >> 9, j = p & 511;
    const float scale = 2.f * PI_F;
    float inv511 = scale / (511.f + 1e-6f);
    float xe = (float)j * inv511, ye = (float)i * inv511;
    float gm = __int_as_float(gmax[0]);
    float ze = dark[p] / (gm + 1e-6f) * scale;
    float x0 = x[p], x1 = x[p + NPIX], x2 = x[p + 2 * NPIX];

    int ky = i >> 1, ylo, yhi; float wyl, wyh;
    if ((i & 1) == 0) { ylo = ky - 1; yhi = ky; wyl = .25f; wyh = .75f; if (ylo < 0) { ylo = 0; wyl = 0.f; wyh = 1.f; } }
    else              { ylo = ky; yhi = ky + 1; wyl = .75f; wyh = .25f; if (yhi > 255) { yhi = 255; wyh = 0.f; wyl = 1.f; } }
    int kx = j >> 1, xlo, xhi; float wxl, wxh;
    if ((j & 1) == 0) { xlo = kx - 1; xhi = kx; wxl = .25f; wxh = .75f; if (xlo < 0) { xlo = 0; wxl = 0.f; wxh = 1.f; } }
    else              { xlo = kx; xhi = kx + 1; wxl = .75f; wxh = .25f; if (xhi > 255) { xhi = 255; wxh = 0.f; wxl = 1.f; } }
    int s00 = ylo * 256 + xlo, s01 = ylo * 256 + xhi, s10 = yhi * 256 + xlo, s11 = yhi * 256 + xhi;
    float w00 = wyl * wxl, w01 = wyl * wxh, w10 = wyh * wxl, w11 = wyh * wxh;

    float a0 = 0.f, a1 = 0.f, a2 = 0.f;
    #pragma unroll 1
    for (int c = 0; c < 64; c++) {
        float e = (c < 16) ? xe / dimt[c] : (c < 32) ? ye / dimt[c - 16] : ze / dimt[c - 32];
        float sn, cs;
        __sincosf(e, &sn, &cs);
        float pos = ((c & 1) == 0) ? sn : cs;
        float ape = pos + w1[c * 3] * x0 + w1[c * 3 + 1] * x1 + w1[c * 3 + 2] * x2 + b1[c];
        const float* gp = g4 + (size_t)c * 65536;
        float gv = w00 * gp[s00] + w01 * gp[s01] + w10 * gp[s10] + w11 * gp[s11];
        float s = gv * ape;
        a0 += wb[c] * s; a1 += wb[64 + c] * s; a2 += wb[128 + c] * s;
    }
    float f0 = w00 * h3[s00] + w01 * h3[s01] + w10 * h3[s10] + w11 * h3[s11];
    const float* h1 = h3 + 65536;
    float f1 = w00 * h1[s00] + w01 * h1[s01] + w10 * h1[s10] + w11 * h1[s11];
    const float* h2 = h3 + 131072;
    float f2 = w00 * h2[s00] + w01 * h2[s01] + w10 * h2[s10] + w11 * h2[s11];
    out[p]            = a0 + f0 + bcs[0] + x0;
    out[NPIX + p]     = a1 + f1 + bcs[1] + x1;
    out[2 * NPIX + p] = a2 + f2 + bcs[2] + x2;
}

// ================================================================ launcher
extern "C" void kernel_launch(void* const* d_in, const int* in_sizes, int n_in,
                              void* d_out, int out_size, void* d_ws, size_t ws_size,
                              hipStream_t stream) {
    const float* x      = (const float*)d_in[0];
    const float* w_cf1  = (const float*)d_in[1];  const float* b_cf1 = (const float*)d_in[2];
    const float* w_e1   = (const float*)d_in[3];  const float* b_e1  = (const float*)d_in[4];
    const float* w_e2   = (const float*)d_in[5];  const float* b_e2  = (const float*)d_in[6];
    const float* w_d1   = (const float*)d_in[7];  const float* b_d1  = (const float*)d_in[8];
    const float* w_d2   = (const float*)d_in[9];  const float* b_d2  = (const float*)d_in[10];
    // 11..14: pha branch is dead code in the reference
    const float* w_amp1 = (const float*)d_in[15]; const float* b_amp1 = (const float*)d_in[16];
    const float* w_amp2 = (const float*)d_in[17]; const float* b_amp2 = (const float*)d_in[18];
    const float* w_sp1  = (const float*)d_in[19]; const float* b_sp1  = (const float*)d_in[20];
    const float* w_sp2  = (const float*)d_in[21]; const float* b_sp2  = (const float*)d_in[22];
    const float* w_u1   = (const float*)d_in[23]; const float* b_u1   = (const float*)d_in[24];
    const float* w_u2   = (const float*)d_in[25]; const float* b_u2   = (const float*)d_in[26];
    const float* w_u3   = (const float*)d_in[27]; const float* b_u3   = (const float*)d_in[28];
    const float* w_u4   = (const float*)d_in[29]; const float* b_u4   = (const float*)d_in[30];
    const float* w_cf2  = (const float*)d_in[31]; const float* b_cf2  = (const float*)d_in[32];
    const float* w_cf3  = (const float*)d_in[33]; const float* b_cf3  = (const float*)d_in[34];
    float* out = (float*)d_out;

    char* ws = (char*)d_ws;
    constexpr size_t MiB = 1ull << 20;
    float*  dark   = (float*)(ws + 0 * MiB);
    float*  tmp    = (float*)(ws + 1 * MiB);
    int*    gmax   = (int*)  (ws + 2 * MiB);
    float*  Wc     = (float*)(ws + 2 * MiB + 1024);
    float*  bc     = (float*)(ws + 2 * MiB + 2560);
    float*  W21c   = (float*)(ws + 2 * MiB + 4096);   // 768 floats
    float*  b21c   = (float*)(ws + 2 * MiB + 7168);
    float*  b43    = (float*)(ws + 2 * MiB + 7424);   // 64 floats
    float*  xfs    = (float*)(ws + 3 * MiB);     // [3,67)  s2d-layout
    float*  xd1    = (float*)(ws + 67 * MiB);    // [67,99)
    float*  xd2    = (float*)(ws + 99 * MiB);    // [99,115)
    float*  F1T    = (float*)(ws + 115 * MiB);   // [115,147)
    float*  F2C    = (float*)(ws + 147 * MiB);   // [147,163.25)
    float*  ampb   = (float*)(ws + 164 * MiB);   // [164,172.125)
    float*  A1     = (float*)(ws + 173 * MiB);   // [173,181.125)
    float*  A2     = (float*)(ws + 182 * MiB);   // [182,190.125)
    float*  Zbuf   = (float*)(ws + 115 * MiB);   // (F1T dead after F2)
    float*  I1T    = (float*)(ws + 132 * MiB);   // [132,149)
    float*  I2T    = (float*)(ws + 149 * MiB);   // [149,165)
    float*  h3s    = (float*)(ws + 11 * MiB);    // [11,11.2)
    float*  h3     = (float*)(ws + 27 * MiB);    // [27,27.75)
    float*  s1     = (float*)(ws + 31 * MiB);    // [31,47)
    float*  s2     = (float*)(ws + 47 * MiB);    // [47,63)
    float*  g4out  = (float*)(ws + 71 * MiB);    // [71,87)
    float*  g4s    = (float*)(ws + 87 * MiB);    // [87,91)
    unsigned short* wb16 = (unsigned short*)(ws + 192 * MiB);
    unsigned short* d1h = wb16 + 0,       * d1l = wb16 + 32768;
    unsigned short* d2h = wb16 + 65536,   * d2l = wb16 + 196608;
    unsigned short* a1h = wb16 + 327680,  * a1l = wb16 + 393216;
    unsigned short* a2h = wb16 + 458752,  * a2l = wb16 + 524288;
    unsigned short* s1h = wb16 + 589824;
    unsigned short* s2h = wb16 + 655360;
    unsigned short* u43h = wb16 + 720896;          // 16384 shorts
    unsigned short* BfH = wb16 + 786432,  * BfL = wb16 + 819200;
    unsigned short* BfcH = wb16 + 851968, * BfcL = wb16 + 917504;
    unsigned short* BicH = wb16 + 983040, * BicL = wb16 + 1048576;
    unsigned short* BirH = wb16 + 1114112,* BirL = wb16 + 1134592;
    float* zbias = (float*)(ws + 195 * MiB + 512 * 1024);

    // 1) dark channel + gmax ; merged prep
    k_minc<<<1024, 256, 0, stream>>>(x, dark, gmax);
    k_minrow<<<1024, 256, 0, stream>>>(dark, tmp);
    k_mincol_max<<<1024, 256, 0, stream>>>(tmp, dark, gmax);
    k_prep<<<2449, 256, 0, stream>>>(
        w_d1, d1h, d1l, w_d2, d2h, d2l, w_amp1, a1h, a1l, w_amp2, a2h, a2l,
        w_sp1, s1h, w_sp2, s2h,
        w_u3, w_u4, u43h, b_u3, b_u4, b43,
        BfH, BfL, BfcH, BfcL, BicH, BicL, BirH, BirL, zbias,
        w_cf2, b_cf2, w_cf3, b_cf3, w_u2, b_u2, w_u1, b_u1, Wc, bc, W21c, b21c);

    // 2) e1/e2 in s2d layout ; d1 coalesced AMODE 0 ; d2 AMODE 1
    k_ef2<<<1024, 256, 0, stream>>>(x, w_e1, b_e1, w_e2, b_e2, xfs);
    k_mmcf<0, 1, 0, 0><<<dim3(512, 2), 256, 0, stream>>>(xfs, d1h, d1l, b_d1, xd1, 65536, 128, 256, 0, 0, 0);
    k_mmcf<1, 1, 0, 0><<<dim3(128, 4), 256, 0, stream>>>(xd1, d2h, d2l, b_d2, xd2, 16384, 256, 512, 7, 7, 256);

    // 3) FFT section as MFMA GEMMs
    k_mmcf<3, 1, 0, 1><<<dim3(256, 4), 256, 0, stream>>>(xd2, BfH, BfL, zbias, F1T, 32768, 256, 128, 0, 0, 0);
    k_mmcf<7, 1, 0, 0><<<dim3(130, 4), 256, 0, stream>>>(F1T, BfcH, BfcL, zbias, F2C, 16640, 256, 256, 0, 0, 0);
    k_ampc<<<32768, 128, 0, stream>>>(F2C, ampb);
    k_mmcf<0, 1, 1, 0><<<dim3(65, 4), 256, 0, stream>>>(ampb, a1h, a1l, b_amp1, A1, 8320, 256, 256, 0, 0, 0);
    k_mmcf<0, 1, 0, 0><<<dim3(65, 4), 256, 0, stream>>>(A1, a2h, a2l, b_amp2, A2, 8320, 256, 256, 0, 0, 0);
    k_zbuild<<<32768, 128, 0, stream>>>(A2, Zbuf);
    k_mmcf<0, 1, 0, 1><<<dim3(130, 4), 256, 0, stream>>>(Zbuf, BicH, BicL, zbias, I1T, 16640, 256, 256, 0, 0, 0);
    k_mmcf<8, 1, 0, 1><<<dim3(256, 2), 256, 0, stream>>>(I1T, BirH, BirL, zbias, I2T, 32768, 128, 160, 0, 0, 0);

    // 4) four path: h3s = W21c @ I2T directly ; resize 3ch
    k_h3s<<<64, 256, 0, stream>>>(I2T, W21c, b21c, h3s);
    k_resize2<<<768, 256, 0, stream>>>(h3s, h3, 3, 128);

    // 5) spat path: sp1, sp2, composed u43 GEMM ; resize 64ch
    k_mmcf<0, 0, 1, 0><<<dim3(128, 4), 256, 0, stream>>>(xd2, s1h, nullptr, b_sp1, s1, 16384, 256, 256, 0, 0, 0);
    k_mmcf<0, 0, 0, 0><<<dim3(128, 4), 256, 0, stream>>>(s1, s2h, nullptr, b_sp2, s2, 16384, 256, 256, 0, 0, 0);
    k_mmcf<0, 0, 0, 0><<<dim3(128, 1), 256, 0, stream>>>(s2, u43h, nullptr, b43, g4s, 16384, 64, 256, 0, 0, 0);
    k_resize2<<<16384, 256, 0, stream>>>(g4s, g4out, 64, 128);

    // 6) final fused stage
    k_final<<<1024, 256, 0, stream>>>(x, dark, gmax, w_cf1, b_cf1, Wc, bc, g4out, h3, out);
}

// Round 15
// 445.018 us; speedup vs baseline: 1.1703x; 1.0450x over previous
//
#include <hip/hip_runtime.h>
#include <math.h>

#define PI_F 3.14159265358979323846f
#define NPIX 262144   // 512*512

typedef __attribute__((ext_vector_type(8))) short sh8;
typedef __attribute__((ext_vector_type(4))) float fx4;

__device__ __forceinline__ unsigned short f2bf(float v) {
    unsigned u = __float_as_uint(v);
    return (unsigned short)((u + 0x7FFFu + ((u >> 16) & 1)) >> 16);
}
__device__ __forceinline__ float bf2f(unsigned short h) {
    return __uint_as_float((unsigned)h << 16);
}

// ---------------------------------------------------------------- dark channel
__global__ __launch_bounds__(256) void k_minc(const float* __restrict__ x, float* __restrict__ dm,
                                              int* __restrict__ gmax) {
    int p = blockIdx.x * 256 + threadIdx.x;
    if (p == 0) gmax[0] = 0;
    float m = fmaxf(x[p], fmaxf(x[p + NPIX], x[p + 2 * NPIX]));
    dm[p] = 1.0f - m;
}

__device__ __forceinline__ int refl512(int t) {
    if (t < 0) t = -t;
    if (t > 511) t = 1022 - t;
    return t;
}

__global__ __launch_bounds__(256) void k_minrow(const float* __restrict__ dm, float* __restrict__ tmp) {
    int p = blockIdx.x * 256 + threadIdx.x;
    int i = p >> 9, j = p & 511;
    float m = 1e30f;
    #pragma unroll
    for (int d = -7; d <= 7; d++) m = fminf(m, dm[(i << 9) + refl512(j + d)]);
    tmp[p] = m;
}

__global__ __launch_bounds__(256) void k_mincol_max(const float* __restrict__ tmp, float* __restrict__ dark,
                                                    int* __restrict__ gmax) {
    int p = blockIdx.x * 256 + threadIdx.x;
    int i = p >> 9, j = p & 511;
    float m = 1e30f;
    #pragma unroll
    for (int d = -7; d <= 7; d++) m = fminf(m, tmp[(refl512(i + d) << 9) + j]);
    dark[p] = m;
    __shared__ float red[256];
    int tid = threadIdx.x;
    red[tid] = m;
    __syncthreads();
    for (int s = 128; s > 0; s >>= 1) {
        if (tid < s) red[tid] = fmaxf(red[tid], red[tid + s]);
        __syncthreads();
    }
    if (tid == 0) atomicMax(gmax, __float_as_int(red[0]));
}

// ---------------------------------------------------------------- prep helpers (device)
__device__ __forceinline__ void prep_one(const float* __restrict__ w, unsigned short* __restrict__ h,
                                         unsigned short* __restrict__ l, int N, int K, int cshift, int idx) {
    if (idx >= N * K) return;
    int n = idx / K, kord = idx - n * K;
    int ksrc = kord;
    if (cshift) {
        int dydx = kord >> cshift, c = kord & ((1 << cshift) - 1);
        ksrc = c * 4 + dydx;
    }
    float v = w[n * K + ksrc];
    unsigned short hb = f2bf(v);
    h[idx] = hb;
    if (l) l[idx] = f2bf(v - bf2f(hb));
}

__device__ __forceinline__ void bfft_one(int idx,
                                         unsigned short* __restrict__ BfH, unsigned short* __restrict__ BfL,
                                         unsigned short* __restrict__ BfcH, unsigned short* __restrict__ BfcL,
                                         unsigned short* __restrict__ BicH, unsigned short* __restrict__ BicL,
                                         unsigned short* __restrict__ BirH, unsigned short* __restrict__ BirL,
                                         float* __restrict__ zbias) {
    if (idx < 256) zbias[idx] = 0.f;
    const float w0 = 2.f * PI_F / 128.f;
    float v;
    unsigned short *H, *L;
    int off;
    if (idx < 32768) {                     // Bf [256][128]
        int n = idx >> 7, k = idx & 127;
        int t = n & 127, r = (t * k) & 127;
        float s_, c_; sincosf(w0 * r, &s_, &c_);
        v = (n < 128) ? c_ : -s_;
        H = BfH; L = BfL; off = idx;
    } else if (idx < 98304) {              // Bfc [256][256]
        int i = idx - 32768;
        int n = i >> 8, j = i & 255;
        int t = n & 127, r = (t * (j & 127)) & 127;
        float s_, c_; sincosf(w0 * r, &s_, &c_);
        v = (n < 128) ? ((j < 128) ? c_ : s_) : ((j < 128) ? -s_ : c_);
        H = BfcH; L = BfcL; off = i;
    } else if (idx < 163840) {             // Bic [256][256]
        int i = idx - 98304;
        int n = i >> 8, j = i & 255;
        int t = n & 127, r = (t * (j & 127)) & 127;
        float s_, c_; sincosf(w0 * r, &s_, &c_);
        v = ((n < 128) ? ((j < 128) ? c_ : -s_) : ((j < 128) ? s_ : c_)) * (1.f / 128.f);
        H = BicH; L = BicL; off = i;
    } else if (idx < 184320) {             // Bir [128][160]
        int i = idx - 163840;
        int col = i / 160, j = i - col * 160;
        if (j == 0) v = 1.f / 128.f;
        else if (j < 64)  { int r = (j * col) & 127; float s_, c_; sincosf(w0 * r, &s_, &c_); v = 2.f * c_ / 128.f; }
        else if (j == 64) v = (col & 1) ? -1.f / 128.f : 1.f / 128.f;
        else if (j >= 66 && j <= 128) { int k = j - 65; int r = (k * col) & 127; float s_, c_; sincosf(w0 * r, &s_, &c_); v = -2.f * s_ / 128.f; }
        else v = 0.f;
        H = BirH; L = BirL; off = i;
    } else return;
    unsigned short hb = f2bf(v);
    H[off] = hb;
    L[off] = f2bf(v - bf2f(hb));
}

// ---------------------------------------------------------------- merged prep kernel
__global__ __launch_bounds__(256) void k_prep(
    const float* __restrict__ w_d1, unsigned short* __restrict__ d1h, unsigned short* __restrict__ d1l,
    const float* __restrict__ w_d2, unsigned short* __restrict__ d2h, unsigned short* __restrict__ d2l,
    const float* __restrict__ w_a1, unsigned short* __restrict__ a1h, unsigned short* __restrict__ a1l,
    const float* __restrict__ w_a2, unsigned short* __restrict__ a2h, unsigned short* __restrict__ a2l,
    const float* __restrict__ w_s1, unsigned short* __restrict__ s1h,
    const float* __restrict__ w_s2, unsigned short* __restrict__ s2h,
    const float* __restrict__ w_u3, const float* __restrict__ w_u4, unsigned short* __restrict__ u43h,
    const float* __restrict__ b_u3, const float* __restrict__ b_u4, float* __restrict__ b43,
    unsigned short* __restrict__ BfH, unsigned short* __restrict__ BfL,
    unsigned short* __restrict__ BfcH, unsigned short* __restrict__ BfcL,
    unsigned short* __restrict__ BicH, unsigned short* __restrict__ BicL,
    unsigned short* __restrict__ BirH, unsigned short* __restrict__ BirL,
    float* __restrict__ zbias,
    const float* __restrict__ w2, const float* __restrict__ b2,
    const float* __restrict__ w3, const float* __restrict__ b3,
    const float* __restrict__ wu2, const float* __restrict__ bu2,
    const float* __restrict__ wu1, const float* __restrict__ bu1,
    float* __restrict__ Wc, float* __restrict__ bc,
    float* __restrict__ W21c, float* __restrict__ b21c) {
    int b = blockIdx.x, tid = threadIdx.x;
    if (b < 128)       prep_one(w_d1, d1h, d1l, 128, 256, 6, b * 256 + tid);
    else if (b < 640)  prep_one(w_d2, d2h, d2l, 256, 512, 7, (b - 128) * 256 + tid);
    else if (b < 896)  prep_one(w_a1, a1h, a1l, 256, 256, 0, (b - 640) * 256 + tid);
    else if (b < 1152) prep_one(w_a2, a2h, a2l, 256, 256, 0, (b - 896) * 256 + tid);
    else if (b < 1408) prep_one(w_s1, s1h, nullptr, 256, 256, 0, (b - 1152) * 256 + tid);
    else if (b < 1664) prep_one(w_s2, s2h, nullptr, 256, 256, 0, (b - 1408) * 256 + tid);
    else if (b < 2384) bfft_one((b - 1664) * 256 + tid, BfH, BfL, BfcH, BfcL, BicH, BicL, BirH, BirL, zbias);
    else if (b < 2448) {
        int idx = (b - 2384) * 256 + tid;
        int n = idx >> 8, j = idx & 255;
        float s = 0.f;
        #pragma unroll 16
        for (int o = 0; o < 128; o++) s += w_u4[n * 128 + o] * w_u3[o * 256 + j];
        u43h[idx] = f2bf(s);
    } else {
        __shared__ float sWc[384], sW2c[384];
        if (tid < 128) {
            int j = tid;
            for (int r = 0; r < 3; r++) {
                float s = 0.f;
                #pragma unroll 16
                for (int o = 0; o < 64; o++) s += w3[r * 64 + o] * w2[o * 128 + j];
                sWc[r * 128 + j] = s;
                Wc[r * 128 + j] = s;
            }
            if (j < 3) {
                float s = b3[j];
                #pragma unroll 16
                for (int o = 0; o < 64; o++) s += w3[j * 64 + o] * b2[o];
                bc[j] = s;
            }
        }
        if (tid >= 128 && tid < 192) {
            int n = tid - 128;
            float s = b_u4[n];
            #pragma unroll 16
            for (int o = 0; o < 128; o++) s += w_u4[n * 128 + o] * b_u3[o];
            b43[n] = s;
        }
        __syncthreads();
        if (tid < 128) {
            int j = tid;
            for (int r = 0; r < 3; r++) {
                float s = 0.f;
                #pragma unroll 16
                for (int o = 0; o < 64; o++) s += sWc[r * 128 + o] * wu2[o * 128 + j];
                sW2c[r * 128 + j] = s;
            }
        }
        __syncthreads();
        if (tid < 256) {
            int j = tid;
            for (int r = 0; r < 3; r++) {
                float s = 0.f;
                #pragma unroll 16
                for (int o = 0; o < 128; o++) s += sW2c[r * 128 + o] * wu1[o * 256 + j];
                W21c[r * 256 + j] = s;
            }
        }
        if (tid < 3) {
            float s = 0.f;
            #pragma unroll 16
            for (int o = 0; o < 128; o++) s += sW2c[tid * 128 + o] * bu1[o];
            #pragma unroll 16
            for (int o = 0; o < 64; o++)  s += sWc[tid * 128 + o] * bu2[o];
            b21c[tid] = s;
        }
    }
}

// ---------------------------------------------------------------- x_f = e2(e1(x)), s2d [kord][m2] layout
__global__ __launch_bounds__(256) void k_ef2(const float* __restrict__ x,
                                             const float* __restrict__ w1, const float* __restrict__ b1,
                                             const float* __restrict__ w2, const float* __restrict__ b2,
                                             float* __restrict__ out) {
    __shared__ float sw1[24], sb1[8], sw2[512], sb2[64];
    int tid = threadIdx.x;
    if (tid < 24) sw1[tid] = w1[tid];
    if (tid < 8)  sb1[tid] = b1[tid];
    if (tid < 64) sb2[tid] = b2[tid];
    if (tid < 256) { sw2[tid] = w2[tid]; sw2[tid + 256] = w2[tid + 256]; }
    __syncthreads();
    int bid = blockIdx.x;
    int dydx = bid >> 8;
    int m2 = (bid & 255) * 256 + tid;
    int i = m2 >> 8, j = m2 & 255;
    int dy = dydx >> 1, dx = dydx & 1;
    int p5 = (2 * i + dy) * 512 + 2 * j + dx;
    float x0 = x[p5], x1 = x[p5 + NPIX], x2 = x[p5 + 2 * NPIX];
    float h[8];
    #pragma unroll
    for (int r = 0; r < 8; r++)
        h[r] = sw1[r * 3] * x0 + sw1[r * 3 + 1] * x1 + sw1[r * 3 + 2] * x2 + sb1[r];
    #pragma unroll 1
    for (int o = 0; o < 64; o++) {
        float acc = sb2[o];
        #pragma unroll
        for (int r = 0; r < 8; r++) acc += sw2[o * 8 + r] * h[r];
        out[(size_t)(dydx * 64 + o) * 65536 + m2] = acc;
    }
}

// ---------------------------------------------------------------- channels-first MFMA GEMM
// C[n][m] (or TSTORE: C[m][n]) = sum_k B[n][k] * A(k, m) + bias[n]
// AMODE 0: A[k][m] [K][M] ; 1: s2d gather ; 3: A[m][K] ; 7: F2 read from F1T ; 8: I2 read from I1T
// A-staging writes vectorized: pack 8 bf16 into sh8, 2 x ds_write_b128 per thread.
template<int AMODE, int SPLIT, int LRELU, int TSTORE>
__global__ __launch_bounds__(256) void k_mmcf(const float* __restrict__ Asrc,
                                              const unsigned short* __restrict__ Bh,
                                              const unsigned short* __restrict__ Bl,
                                              const float* __restrict__ bias, float* __restrict__ C,
                                              int M, int N, int K, int cshift, int wshift, int srcW) {
    __shared__ unsigned short AhS[128 * 40];
    __shared__ unsigned short BhS[64 * 40];
    __shared__ unsigned short AlS[SPLIT ? 128 * 40 : 8];
    __shared__ unsigned short BlS[SPLIT ? 64 * 40 : 8];
    int tid = threadIdx.x;
    int m0 = blockIdx.x * 128;
    int n0 = blockIdx.y * 64;
    int wave = tid >> 6, lane = tid & 63;
    int wm = (wave >> 1) * 64, wn = (wave & 1) * 32;
    int l15 = lane & 15, quad = lane >> 4;
    int lk = quad * 8, lk4 = quad * 4;
    fx4 acc[4][2];
    #pragma unroll
    for (int a = 0; a < 4; a++)
        #pragma unroll
        for (int b = 0; b < 2; b++)
            acc[a][b] = (fx4){0.f, 0.f, 0.f, 0.f};

    int mm = tid & 127;
    int kpb = tid >> 7;
    int gm = m0 + mm;
    int oj = 0, oi = 0, cA = 0, kfA = 0, tauA = 0;
    size_t abase = 0;
    if (AMODE == 1) { oj = gm & ((1 << wshift) - 1); oi = gm >> wshift; }
    if (AMODE == 3) abase = (size_t)gm * K;
    if (AMODE == 7) { cA = gm / 65; kfA = gm - cA * 65; }
    if (AMODE == 8) { cA = gm >> 7; tauA = gm & 127; }

    for (int kb = 0; kb < K; kb += 32) {
        #pragma unroll
        for (int half = 0; half < 2; half++) {
            sh8 hv, lv;
            #pragma unroll
            for (int tt = 0; tt < 4; tt++) {
                int kp = kpb * 8 + half * 4 + tt;
                int k0 = kb + kp * 2;
                float a0, a1;
                if (AMODE == 0) {
                    a0 = Asrc[(size_t)k0 * M + gm];
                    a1 = Asrc[(size_t)(k0 + 1) * M + gm];
                } else if (AMODE == 1) {
                    int c = k0 & ((1 << cshift) - 1);
                    int dydx = k0 >> cshift;
                    int dy = dydx >> 1, dx = dydx & 1;
                    size_t pix = (size_t)(2 * oi + dy) * srcW + (2 * oj + dx);
                    size_t plane = (size_t)srcW * srcW;
                    a0 = Asrc[(size_t)c * plane + pix];
                    a1 = Asrc[(size_t)(c + 1) * plane + pix];
                } else if (AMODE == 3) {
                    a0 = Asrc[abase + k0];
                    a1 = Asrc[abase + k0 + 1];
                } else if (AMODE == 7) {
                    int t0 = k0 & 127, hf = k0 >> 7;
                    size_t ad = (size_t)(cA * 128 + t0) * 256 + hf * 128 + kfA;
                    a0 = Asrc[ad];
                    a1 = Asrc[ad + 256];
                } else {                       // AMODE 8
                    int j0 = k0, j1 = k0 + 1;
                    int kf0 = (j0 < 65) ? j0 : ((j0 < 130) ? j0 - 65 : 0);
                    int hf0 = (j0 >= 65 && j0 < 130) ? 1 : 0;
                    int kf1 = (j1 < 65) ? j1 : ((j1 < 130) ? j1 - 65 : 0);
                    int hf1 = (j1 >= 65 && j1 < 130) ? 1 : 0;
                    a0 = Asrc[(size_t)(cA * 65 + kf0) * 256 + hf0 * 128 + tauA];
                    a1 = Asrc[(size_t)(cA * 65 + kf1) * 256 + hf1 * 128 + tauA];
                }
                unsigned short h0 = f2bf(a0), h1 = f2bf(a1);
                hv[tt * 2] = (short)h0;
                hv[tt * 2 + 1] = (short)h1;
                if (SPLIT) {
                    lv[tt * 2] = (short)f2bf(a0 - bf2f(h0));
                    lv[tt * 2 + 1] = (short)f2bf(a1 - bf2f(h1));
                }
            }
            int coff = (kpb * 2 + half) * 8;
            *(sh8*)(void*)&AhS[mm * 40 + coff] = hv;
            if (SPLIT) *(sh8*)(void*)&AlS[mm * 40 + coff] = lv;
        }
        {
            int n = tid >> 2, seg = tid & 3;
            size_t gb = (size_t)(n0 + n) * K + kb + seg * 8;
            *(sh8*)(void*)&BhS[n * 40 + seg * 8] = *(const sh8*)(const void*)&Bh[gb];
            if (SPLIT) *(sh8*)(void*)&BlS[n * 40 + seg * 8] = *(const sh8*)(const void*)&Bl[gb];
        }
        __syncthreads();
        sh8 af[4], bf[2], afl[4], bfl[2];
        #pragma unroll
        for (int mt = 0; mt < 4; mt++) {
            af[mt] = *(const sh8*)(const void*)&AhS[(wm + mt * 16 + l15) * 40 + lk];
            if (SPLIT) afl[mt] = *(const sh8*)(const void*)&AlS[(wm + mt * 16 + l15) * 40 + lk];
        }
        #pragma unroll
        for (int nt = 0; nt < 2; nt++) {
            bf[nt] = *(const sh8*)(const void*)&BhS[(wn + nt * 16 + l15) * 40 + lk];
            if (SPLIT) bfl[nt] = *(const sh8*)(const void*)&BlS[(wn + nt * 16 + l15) * 40 + lk];
        }
        #pragma unroll
        for (int mt = 0; mt < 4; mt++)
            #pragma unroll
            for (int nt = 0; nt < 2; nt++) {
                acc[mt][nt] = __builtin_amdgcn_mfma_f32_16x16x32_bf16(af[mt], bf[nt], acc[mt][nt], 0, 0, 0);
                if (SPLIT) {
                    acc[mt][nt] = __builtin_amdgcn_mfma_f32_16x16x32_bf16(af[mt], bfl[nt], acc[mt][nt], 0, 0, 0);
                    acc[mt][nt] = __builtin_amdgcn_mfma_f32_16x16x32_bf16(afl[mt], bf[nt], acc[mt][nt], 0, 0, 0);
                }
            }
        __syncthreads();
    }
    #pragma unroll
    for (int nt = 0; nt < 2; nt++) {
        int n = n0 + wn + nt * 16 + l15;
        float bs = bias[n];
        #pragma unroll
        for (int mt = 0; mt < 4; mt++) {
            int mbase = m0 + wm + mt * 16 + lk4;
            if (TSTORE) {
                #pragma unroll
                for (int r = 0; r < 4; r++) {
                    float q = acc[mt][nt][r] + bs;
                    if (LRELU) q = (q < 0.f) ? 0.1f * q : q;
                    C[(size_t)(mbase + r) * N + n] = q;
                }
            } else {
                float4 v;
                float* vp = (float*)&v;
                #pragma unroll
                for (int r = 0; r < 4; r++) {
                    float q = acc[mt][nt][r] + bs;
                    if (LRELU) q = (q < 0.f) ? 0.1f * q : q;
                    vp[r] = q;
                }
                *(float4*)&C[(size_t)n * M + mbase] = v;
            }
        }
    }
}

// ---------------------------------------------------------------- amp = sqrt(re^2+im^2), layout -> [c][t][kf]
__global__ __launch_bounds__(128) void k_ampc(const float* __restrict__ F2C, float* __restrict__ ampb) {
    int bid = blockIdx.x;
    int kf = threadIdx.x;
    if (kf >= 65) return;
    int c = bid >> 7, t = bid & 127;
    size_t m = (size_t)c * 65 + kf;
    float re = F2C[(size_t)t * 16640 + m];
    float im = F2C[(size_t)(t + 128) * 16640 + m];
    ampb[(size_t)bid * 65 + kf] = sqrtf(re * re + im * im);
}

// ---------------------------------------------------------------- z = a*(cos a, sin a) -> stacked [t][(c,kf)] planes
__global__ __launch_bounds__(128) void k_zbuild(const float* __restrict__ A2, float* __restrict__ Z) {
    int bid = blockIdx.x;
    int kf = threadIdx.x;
    if (kf >= 65) return;
    int c = bid >> 7, t = bid & 127;
    float a = A2[(size_t)bid * 65 + kf];
    float s_, c_;
    sincosf(a, &s_, &c_);
    size_t m = (size_t)c * 65 + kf;
    Z[(size_t)t * 16640 + m] = a * c_;
    Z[2129920 + (size_t)t * 16640 + m] = a * s_;
}

// ---------------------------------------------------------------- h3s = W21c @ I2T + b21c  (3ch @128^2, K=256)
__global__ __launch_bounds__(256) void k_h3s(const float* __restrict__ I2T, const float* __restrict__ W21c,
                                             const float* __restrict__ b21c, float* __restrict__ h3s) {
    __shared__ float wa[768], bs[3];
    int tid = threadIdx.x;
    for (int i = tid; i < 768; i += 256) wa[i] = W21c[i];
    if (tid < 3) bs[tid] = b21c[tid];
    __syncthreads();
    int q = blockIdx.x * 256 + tid;
    float a0 = bs[0], a1 = bs[1], a2 = bs[2];
    #pragma unroll 4
    for (int c = 0; c < 256; c++) {
        float v = I2T[(size_t)c * 16384 + q];
        a0 += wa[c] * v;
        a1 += wa[256 + c] * v;
        a2 += wa[512 + c] * v;
    }
    h3s[q] = a0; h3s[16384 + q] = a1; h3s[32768 + q] = a2;
}

// ---------------------------------------------------------------- channels-first bilinear x2 resize
__global__ __launch_bounds__(256) void k_resize2(const float* __restrict__ src, float* __restrict__ dst,
                                                 int C, int H) {
    int W2 = 2 * H;
    size_t idx = (size_t)blockIdx.x * 256 + threadIdx.x;
    size_t plane = (size_t)W2 * W2;
    if (idx >= (size_t)C * plane) return;
    int c = (int)(idx / plane);
    int rem = (int)(idx - (size_t)c * plane);
    int i = rem / W2, j = rem - i * W2;
    int ky = i >> 1, ylo, yhi; float wyl, wyh;
    if ((i & 1) == 0) { ylo = ky - 1; yhi = ky; wyl = .25f; wyh = .75f; if (ylo < 0) { ylo = 0; wyl = 0.f; wyh = 1.f; } }
    else              { ylo = ky; yhi = ky + 1; wyl = .75f; wyh = .25f; if (yhi > H - 1) { yhi = H - 1; wyh = 0.f; wyl = 1.f; } }
    int kx = j >> 1, xlo, xhi; float wxl, wxh;
    if ((j & 1) == 0) { xlo = kx - 1; xhi = kx; wxl = .25f; wxh = .75f; if (xlo < 0) { xlo = 0; wxl = 0.f; wxh = 1.f; } }
    else              { xlo = kx; xhi = kx + 1; wxl = .75f; wxh = .25f; if (xhi > H - 1) { xhi = H - 1; wxh = 0.f; wxl = 1.f; } }
    const float* p = src + (size_t)c * H * H;
    dst[idx] = wyl * (wxl * p[(size_t)ylo * H + xlo] + wxh * p[(size_t)ylo * H + xhi]) +
               wyh * (wxl * p[(size_t)yhi * H + xlo] + wxh * p[(size_t)yhi * H + xhi]);
}

// ---------------------------------------------------------------- final fused stage @512^2
__global__ __launch_bounds__(256) void k_final(const float* __restrict__ x,
                                               const float* __restrict__ dark, const int* __restrict__ gmax,
                                               const float* __restrict__ wcf1, const float* __restrict__ bcf1,
                                               const float* __restrict__ Wc, const float* __restrict__ bc,
                                               const float* __restrict__ g4, const float* __restrict__ h3,
                                               float* __restrict__ out) {
    __shared__ float dimt[32], w1[192], b1[64], wb[192], bcs[3];
    int tid = threadIdx.x;
    if (tid < 32) dimt[tid] = powf(10000.f, (float)(2 * (tid >> 1)) / 32.f);
    if (tid < 192) w1[tid] = wcf1[tid];
    if (tid < 64) b1[tid] = bcf1[tid];
    if (tid < 192) { int r = tid / 64, c = tid - (tid / 64) * 64; wb[tid] = Wc[r * 128 + 64 + c]; }
    if (tid < 3) bcs[tid] = bc[tid];
    __syncthreads();
    int p = blockIdx.x * 256 + tid;
    int i = p >> 9, j = p & 511;
    const float scale = 2.f * PI_F;
    float inv511 = scale / (511.f + 1e-6f);
    float xe = (float)j * inv511, ye = (float)i * inv511;
    float gm = __int_as_float(gmax[0]);
    float ze = dark[p] / (gm + 1e-6f) * scale;
    float x0 = x[p], x1 = x[p + NPIX], x2 = x[p + 2 * NPIX];

    int ky = i >> 1, ylo, yhi; float wyl, wyh;
    if ((i & 1) == 0) { ylo = ky - 1; yhi = ky; wyl = .25f; wyh = .75f; if (ylo < 0) { ylo = 0; wyl = 0.f; wyh = 1.f; } }
    else              { ylo = ky; yhi = ky + 1; wyl = .75f; wyh = .25f; if (yhi > 255) { yhi = 255; wyh = 0.f; wyl = 1.f; } }
    int kx = j >> 1, xlo, xhi; float wxl, wxh;
    if ((j & 1) == 0) { xlo = kx - 1; xhi = kx; wxl = .25f; wxh = .75f; if (xlo < 0) { xlo = 0; wxl = 0.f; wxh = 1.f; } }
    else              { xlo = kx; xhi = kx + 1; wxl = .75f; wxh = .25f; if (xhi > 255) { xhi = 255; wxh = 0.f; wxl = 1.f; } }
    int s00 = ylo * 256 + xlo, s01 = ylo * 256 + xhi, s10 = yhi * 256 + xlo, s11 = yhi * 256 + xhi;
    float w00 = wyl * wxl, w01 = wyl * wxh, w10 = wyh * wxl, w11 = wyh * wxh;

    float a0 = 0.f, a1 = 0.f, a2 = 0.f;
    #pragma unroll 1
    for (int c = 0; c < 64; c++) {
        float e = (c < 16) ? xe / dimt[c] : (c < 32) ? ye / dimt[c - 16] : ze / dimt[c - 32];
        float sn, cs;
        __sincosf(e, &sn, &cs);
        float pos = ((c & 1) == 0) ? sn : cs;
        float ape = pos + w1[c * 3] * x0 + w1[c * 3 + 1] * x1 + w1[c * 3 + 2] * x2 + b1[c];
        const float* gp = g4 + (size_t)c * 65536;
        float gv = w00 * gp[s00] + w01 * gp[s01] + w10 * gp[s10] + w11 * gp[s11];
        float s = gv * ape;
        a0 += wb[c] * s; a1 += wb[64 + c] * s; a2 += wb[128 + c] * s;
    }
    float f0 = w00 * h3[s00] + w01 * h3[s01] + w10 * h3[s10] + w11 * h3[s11];
    const float* h1 = h3 + 65536;
    float f1 = w00 * h1[s00] + w01 * h1[s01] + w10 * h1[s10] + w11 * h1[s11];
    const float* h2 = h3 + 131072;
    float f2 = w00 * h2[s00] + w01 * h2[s01] + w10 * h2[s10] + w11 * h2[s11];
    out[p]            = a0 + f0 + bcs[0] + x0;
    out[NPIX + p]     = a1 + f1 + bcs[1] + x1;
    out[2 * NPIX + p] = a2 + f2 + bcs[2] + x2;
}

// ================================================================ launcher
extern "C" void kernel_launch(void* const* d_in, const int* in_sizes, int n_in,
                              void* d_out, int out_size, void* d_ws, size_t ws_size,
                              hipStream_t stream) {
    const float* x      = (const float*)d_in[0];
    const float* w_cf1  = (const float*)d_in[1];  const float* b_cf1 = (const float*)d_in[2];
    const float* w_e1   = (const float*)d_in[3];  const float* b_e1  = (const float*)d_in[4];
    const float* w_e2   = (const float*)d_in[5];  const float* b_e2  = (const float*)d_in[6];
    const float* w_d1   = (const float*)d_in[7];  const float* b_d1  = (const float*)d_in[8];
    const float* w_d2   = (const float*)d_in[9];  const float* b_d2  = (const float*)d_in[10];
    // 11..14: pha branch is dead code in the reference
    const float* w_amp1 = (const float*)d_in[15]; const float* b_amp1 = (const float*)d_in[16];
    const float* w_amp2 = (const float*)d_in[17]; const float* b_amp2 = (const float*)d_in[18];
    const float* w_sp1  = (const float*)d_in[19]; const float* b_sp1  = (const float*)d_in[20];
    const float* w_sp2  = (const float*)d_in[21]; const float* b_sp2  = (const float*)d_in[22];
    const float* w_u1   = (const float*)d_in[23]; const float* b_u1   = (const float*)d_in[24];
    const float* w_u2   = (const float*)d_in[25]; const float* b_u2   = (const float*)d_in[26];
    const float* w_u3   = (const float*)d_in[27]; const float* b_u3   = (const float*)d_in[28];
    const float* w_u4   = (const float*)d_in[29]; const float* b_u4   = (const float*)d_in[30];
    const float* w_cf2  = (const float*)d_in[31]; const float* b_cf2  = (const float*)d_in[32];
    const float* w_cf3  = (const float*)d_in[33]; const float* b_cf3  = (const float*)d_in[34];
    float* out = (float*)d_out;

    char* ws = (char*)d_ws;
    constexpr size_t MiB = 1ull << 20;
    float*  dark   = (float*)(ws + 0 * MiB);
    float*  tmp    = (float*)(ws + 1 * MiB);
    int*    gmax   = (int*)  (ws + 2 * MiB);
    float*  Wc     = (float*)(ws + 2 * MiB + 1024);
    float*  bc     = (float*)(ws + 2 * MiB + 2560);
    float*  W21c   = (float*)(ws + 2 * MiB + 4096);
    float*  b21c   = (float*)(ws + 2 * MiB + 7168);
    float*  b43    = (float*)(ws + 2 * MiB + 7424);
    float*  xfs    = (float*)(ws + 3 * MiB);     // [3,67)
    float*  xd1    = (float*)(ws + 67 * MiB);    // [67,99)
    float*  xd2    = (float*)(ws + 99 * MiB);    // [99,115)
    float*  F1T    = (float*)(ws + 115 * MiB);   // [115,147)
    float*  F2C    = (float*)(ws + 147 * MiB);   // [147,163.25)
    float*  ampb   = (float*)(ws + 164 * MiB);   // [164,172.125)
    float*  A1     = (float*)(ws + 173 * MiB);   // [173,181.125)
    float*  A2     = (float*)(ws + 182 * MiB);   // [182,190.125)
    float*  Zbuf   = (float*)(ws + 115 * MiB);   // (F1T dead after F2)
    float*  I1T    = (float*)(ws + 132 * MiB);   // [132,149)
    float*  I2T    = (float*)(ws + 149 * MiB);   // [149,165)
    float*  h3s    = (float*)(ws + 11 * MiB);
    float*  h3     = (float*)(ws + 27 * MiB);
    float*  s1     = (float*)(ws + 31 * MiB);
    float*  s2     = (float*)(ws + 47 * MiB);
    float*  g4out  = (float*)(ws + 71 * MiB);
    float*  g4s    = (float*)(ws + 87 * MiB);
    unsigned short* wb16 = (unsigned short*)(ws + 192 * MiB);
    unsigned short* d1h = wb16 + 0,       * d1l = wb16 + 32768;
    unsigned short* d2h = wb16 + 65536,   * d2l = wb16 + 196608;
    unsigned short* a1h = wb16 + 327680,  * a1l = wb16 + 393216;
    unsigned short* a2h = wb16 + 458752,  * a2l = wb16 + 524288;
    unsigned short* s1h = wb16 + 589824;
    unsigned short* s2h = wb16 + 655360;
    unsigned short* u43h = wb16 + 720896;
    unsigned short* BfH = wb16 + 786432,  * BfL = wb16 + 819200;
    unsigned short* BfcH = wb16 + 851968, * BfcL = wb16 + 917504;
    unsigned short* BicH = wb16 + 983040, * BicL = wb16 + 1048576;
    unsigned short* BirH = wb16 + 1114112,* BirL = wb16 + 1134592;
    float* zbias = (float*)(ws + 195 * MiB + 512 * 1024);

    // 1) dark channel + gmax ; merged prep
    k_minc<<<1024, 256, 0, stream>>>(x, dark, gmax);
    k_minrow<<<1024, 256, 0, stream>>>(dark, tmp);
    k_mincol_max<<<1024, 256, 0, stream>>>(tmp, dark, gmax);
    k_prep<<<2449, 256, 0, stream>>>(
        w_d1, d1h, d1l, w_d2, d2h, d2l, w_amp1, a1h, a1l, w_amp2, a2h, a2l,
        w_sp1, s1h, w_sp2, s2h,
        w_u3, w_u4, u43h, b_u3, b_u4, b43,
        BfH, BfL, BfcH, BfcL, BicH, BicL, BirH, BirL, zbias,
        w_cf2, b_cf2, w_cf3, b_cf3, w_u2, b_u2, w_u1, b_u1, Wc, bc, W21c, b21c);

    // 2) e1/e2 in s2d layout ; d1 coalesced (bf16) ; d2 (bf16)
    k_ef2<<<1024, 256, 0, stream>>>(x, w_e1, b_e1, w_e2, b_e2, xfs);
    k_mmcf<0, 0, 0, 0><<<dim3(512, 2), 256, 0, stream>>>(xfs, d1h, nullptr, b_d1, xd1, 65536, 128, 256, 0, 0, 0);
    k_mmcf<1, 0, 0, 0><<<dim3(128, 4), 256, 0, stream>>>(xd1, d2h, nullptr, b_d2, xd2, 16384, 256, 512, 7, 7, 256);

    // 3) FFT section (bf16 DFT GEMMs; amp MLP stays split-bf16 for phase safety)
    k_mmcf<3, 0, 0, 1><<<dim3(256, 4), 256, 0, stream>>>(xd2, BfH, nullptr, zbias, F1T, 32768, 256, 128, 0, 0, 0);
    k_mmcf<7, 0, 0, 0><<<dim3(130, 4), 256, 0, stream>>>(F1T, BfcH, nullptr, zbias, F2C, 16640, 256, 256, 0, 0, 0);
    k_ampc<<<32768, 128, 0, stream>>>(F2C, ampb);
    k_mmcf<0, 1, 1, 0><<<dim3(65, 4), 256, 0, stream>>>(ampb, a1h, a1l, b_amp1, A1, 8320, 256, 256, 0, 0, 0);
    k_mmcf<0, 1, 0, 0><<<dim3(65, 4), 256, 0, stream>>>(A1, a2h, a2l, b_amp2, A2, 8320, 256, 256, 0, 0, 0);
    k_zbuild<<<32768, 128, 0, stream>>>(A2, Zbuf);
    k_mmcf<0, 0, 0, 1><<<dim3(130, 4), 256, 0, stream>>>(Zbuf, BicH, nullptr, zbias, I1T, 16640, 256, 256, 0, 0, 0);
    k_mmcf<8, 0, 0, 1><<<dim3(256, 2), 256, 0, stream>>>(I1T, BirH, nullptr, zbias, I2T, 32768, 128, 160, 0, 0, 0);

    // 4) four path: h3s = W21c @ I2T ; resize 3ch
    k_h3s<<<64, 256, 0, stream>>>(I2T, W21c, b21c, h3s);
    k_resize2<<<768, 256, 0, stream>>>(h3s, h3, 3, 128);

    // 5) spat path: sp1, sp2, composed u43 GEMM ; resize 64ch
    k_mmcf<0, 0, 1, 0><<<dim3(128, 4), 256, 0, stream>>>(xd2, s1h, nullptr, b_sp1, s1, 16384, 256, 256, 0, 0, 0);
    k_mmcf<0, 0, 0, 0><<<dim3(128, 4), 256, 0, stream>>>(s1, s2h, nullptr, b_sp2, s2, 16384, 256, 256, 0, 0, 0);
    k_mmcf<0, 0, 0, 0><<<dim3(128, 1), 256, 0, stream>>>(s2, u43h, nullptr, b43, g4s, 16384, 64, 256, 0, 0, 0);
    k_resize2<<<16384, 256, 0, stream>>>(g4s, g4out, 64, 128);

    // 6) final fused stage
    k_final<<<1024, 256, 0, stream>>>(x, dark, gmax, w_cf1, b_cf1, Wc, bc, g4out, h3, out);
}